// Round 1
// baseline (543.773 us; speedup 1.0000x reference)
//
#include <hip/hip_runtime.h>
#include <hip/hip_bf16.h>
#include <math.h>

#define N_NODES 20000
#define N_EDGES 320000
#define IN_F 256
#define HID 64
#define HEADS 4
#define OUT_F 64
#define EDGE_F 16
#define NUM_CLASSES 10
#define NUM_GRAPHS 40
#define LRELU_ALPHA 0.2f

// ---------------- CSR build (edge list -> sorted-by-src permutation) ----------------
__global__ void count_kernel(const int* __restrict__ src, int* __restrict__ cnt) {
    int e = blockIdx.x * blockDim.x + threadIdx.x;
    if (e < N_EDGES) atomicAdd(&cnt[src[e]], 1);
}

__global__ void scan_kernel(const int* __restrict__ cnt, int* __restrict__ row_ptr) {
    __shared__ int tmp[1024];
    __shared__ int carry;
    int t = threadIdx.x;
    if (t == 0) { carry = 0; row_ptr[0] = 0; }
    __syncthreads();
    for (int base = 0; base < N_NODES; base += 1024) {
        int v = (base + t < N_NODES) ? cnt[base + t] : 0;
        tmp[t] = v;
        __syncthreads();
        for (int off = 1; off < 1024; off <<= 1) {
            int x = (t >= off) ? tmp[t - off] : 0;
            __syncthreads();
            tmp[t] += x;
            __syncthreads();
        }
        if (base + t < N_NODES) row_ptr[base + t + 1] = tmp[t] + carry;
        __syncthreads();
        if (t == 0) carry += tmp[1023];
        __syncthreads();
    }
}

__global__ void scatter_kernel(const int* __restrict__ src, const int* __restrict__ row_ptr,
                               int* __restrict__ cursor, int* __restrict__ perm) {
    int e = blockIdx.x * blockDim.x + threadIdx.x;
    if (e < N_EDGES) {
        int s = src[e];
        int pos = row_ptr[s] + atomicAdd(&cursor[s], 1);
        perm[pos] = e;
    }
}

// ---------------- fp32 tiled GEMM: C[MxN] = A[MxK] * B[KxN] ----------------
// K % 16 == 0, N % 64 == 0; M guarded.
#define BM 64
#define BN 64
#define BK 16
__global__ __launch_bounds__(256) void gemm_f32(const float* __restrict__ A,
                                                const float* __restrict__ B,
                                                float* __restrict__ C,
                                                int M, int N, int K) {
    __shared__ float As[BK][BM + 4];  // transposed A tile; +4 keeps rows 16B-aligned
    __shared__ float Bs[BK][BN];
    int tid = threadIdx.x;
    int tx = tid & 15, ty = tid >> 4;
    int bm = blockIdx.x * BM, bn = blockIdx.y * BN;
    float c[4][4] = {};
    int ar = tid >> 2, ac = (tid & 3) * 4;   // A load: row 0..63, col base 0/4/8/12
    int br = tid >> 4, bc = (tid & 15) * 4;  // B load: row 0..15, col base

    for (int k0 = 0; k0 < K; k0 += BK) {
        float4 av = make_float4(0.f, 0.f, 0.f, 0.f);
        if (bm + ar < M) av = *(const float4*)(A + (size_t)(bm + ar) * K + k0 + ac);
        As[ac + 0][ar] = av.x; As[ac + 1][ar] = av.y;
        As[ac + 2][ar] = av.z; As[ac + 3][ar] = av.w;
        float4 bv = *(const float4*)(B + (size_t)(k0 + br) * N + bn + bc);
        *(float4*)&Bs[br][bc] = bv;
        __syncthreads();
#pragma unroll
        for (int kk = 0; kk < BK; ++kk) {
            float4 a4 = *(const float4*)&As[kk][ty * 4];
            float4 b4 = *(const float4*)&Bs[kk][tx * 4];
            float a[4] = {a4.x, a4.y, a4.z, a4.w};
            float b[4] = {b4.x, b4.y, b4.z, b4.w};
#pragma unroll
            for (int i = 0; i < 4; ++i)
#pragma unroll
                for (int j = 0; j < 4; ++j) c[i][j] += a[i] * b[j];
        }
        __syncthreads();
    }
#pragma unroll
    for (int i = 0; i < 4; ++i) {
        int r = bm + ty * 4 + i;
        if (r < M) {
#pragma unroll
            for (int j = 0; j < 4; ++j) C[(size_t)r * N + bn + tx * 4 + j] = c[i][j];
        }
    }
}

// ---------------- per-node attention scores: s_i, s_j ----------------
__global__ void node_scores(const float* __restrict__ Wh, const float* __restrict__ a,
                            float* __restrict__ si, float* __restrict__ sj) {
    __shared__ float sa[HEADS * 144];
    int tid = threadIdx.x;
    for (int i = tid; i < HEADS * 144; i += blockDim.x) sa[i] = a[i];
    __syncthreads();
    int gid = blockIdx.x * blockDim.x + tid;
    if (gid >= N_NODES * HEADS) return;
    int h = gid & 3;
    const float* w = Wh + (size_t)(gid >> 2) * 256 + h * 64;
    const float* ai = sa + h * 144;
    const float* aj = ai + 64;
    float s0 = 0.f, s1 = 0.f;
#pragma unroll
    for (int d = 0; d < 64; d += 4) {
        float4 wv = *(const float4*)(w + d);
        s0 += wv.x * ai[d] + wv.y * ai[d + 1] + wv.z * ai[d + 2] + wv.w * ai[d + 3];
        s1 += wv.x * aj[d] + wv.y * aj[d + 1] + wv.z * aj[d + 2] + wv.w * aj[d + 3];
    }
    si[gid] = s0;
    sj[gid] = s1;
}

// ---------------- per-edge scores: s_e = edge_attr @ a_e^T ----------------
__global__ void edge_scores(const float* __restrict__ ea, const float* __restrict__ a,
                            float* __restrict__ se) {
    __shared__ float sae[HEADS * EDGE_F];
    int tid = threadIdx.x;
    if (tid < HEADS * EDGE_F) {
        int h = tid / EDGE_F, k = tid % EDGE_F;
        sae[tid] = a[h * 144 + 128 + k];
    }
    __syncthreads();
    int e = blockIdx.x * blockDim.x + tid;
    if (e >= N_EDGES) return;
    float x[16];
#pragma unroll
    for (int k = 0; k < 16; k += 4) {
        float4 v = *(const float4*)(ea + (size_t)e * 16 + k);
        x[k] = v.x; x[k + 1] = v.y; x[k + 2] = v.z; x[k + 3] = v.w;
    }
    float4 o;
    float* op = &o.x;
#pragma unroll
    for (int h = 0; h < HEADS; ++h) {
        float s = 0.f;
#pragma unroll
        for (int k = 0; k < 16; ++k) s += x[k] * sae[h * 16 + k];
        op[h] = s;
    }
    *(float4*)(se + (size_t)e * 4) = o;
}

// ---------------- edge aggregation, 4 heads, concat + ELU ----------------
// one wave per node; lane l holds dim l of each head
__global__ __launch_bounds__(256) void edge_agg_concat(
    const float* __restrict__ Wh, const float* __restrict__ si, const float* __restrict__ sj,
    const float* __restrict__ se, const int* __restrict__ row_ptr, const int* __restrict__ perm,
    const int* __restrict__ dst, float* __restrict__ out) {
    int v = blockIdx.x * 4 + (threadIdx.x >> 6);
    if (v >= N_NODES) return;
    int lane = threadIdx.x & 63;
    float4 siv = *(const float4*)(si + (size_t)v * 4);
    float a0 = 0.f, a1 = 0.f, a2 = 0.f, a3 = 0.f;
    int end = row_ptr[v + 1];
    for (int i = row_ptr[v]; i < end; ++i) {
        int e = perm[i];
        int u = dst[e];
        float4 sjv = *(const float4*)(sj + (size_t)u * 4);
        float4 sev = *(const float4*)(se + (size_t)e * 4);
        float t0 = siv.x + sjv.x + sev.x;
        float t1 = siv.y + sjv.y + sev.y;
        float t2 = siv.z + sjv.z + sev.z;
        float t3 = siv.w + sjv.w + sev.w;
        t0 = t0 > 0.f ? t0 : LRELU_ALPHA * t0;
        t1 = t1 > 0.f ? t1 : LRELU_ALPHA * t1;
        t2 = t2 > 0.f ? t2 : LRELU_ALPHA * t2;
        t3 = t3 > 0.f ? t3 : LRELU_ALPHA * t3;
        float m = fmaxf(fmaxf(t0, t1), fmaxf(t2, t3));
        float p0 = __expf(t0 - m), p1 = __expf(t1 - m), p2 = __expf(t2 - m), p3 = __expf(t3 - m);
        float inv = 1.0f / (p0 + p1 + p2 + p3);
        const float* w = Wh + (size_t)u * 256 + lane;
        a0 += p0 * inv * w[0];
        a1 += p1 * inv * w[64];
        a2 += p2 * inv * w[128];
        a3 += p3 * inv * w[192];
    }
    float* o = out + (size_t)v * 256 + lane;
    o[0]   = a0 > 0.f ? a0 : __expf(a0) - 1.0f;
    o[64]  = a1 > 0.f ? a1 : __expf(a1) - 1.0f;
    o[128] = a2 > 0.f ? a2 : __expf(a2) - 1.0f;
    o[192] = a3 > 0.f ? a3 : __expf(a3) - 1.0f;
}

// ---------------- edge aggregation, single head (att == 1), no activation ----------------
__global__ __launch_bounds__(256) void edge_agg_single(
    const float* __restrict__ Wh, const int* __restrict__ row_ptr, const int* __restrict__ perm,
    const int* __restrict__ dst, float* __restrict__ out) {
    int v = blockIdx.x * 4 + (threadIdx.x >> 6);
    if (v >= N_NODES) return;
    int lane = threadIdx.x & 63;
    float acc = 0.f;
    int end = row_ptr[v + 1];
    for (int i = row_ptr[v]; i < end; ++i) {
        int u = dst[perm[i]];
        acc += Wh[(size_t)u * 64 + lane];
    }
    out[(size_t)v * 64 + lane] = acc;
}

// ---------------- mean pool per graph (batch sorted) ----------------
__global__ void pool_kernel(const float* __restrict__ h3, const int* __restrict__ batch,
                            float* __restrict__ pooled) {
    int g = blockIdx.x;
    int lane = threadIdx.x;
    int lo = 0, hi = N_NODES;
    while (lo < hi) { int mid = (lo + hi) >> 1; if (batch[mid] < g) lo = mid + 1; else hi = mid; }
    int start = lo;
    lo = start; hi = N_NODES;
    while (lo < hi) { int mid = (lo + hi) >> 1; if (batch[mid] < g + 1) lo = mid + 1; else hi = mid; }
    int endi = lo;
    float s = 0.f;
    for (int v = start; v < endi; ++v) s += h3[(size_t)v * 64 + lane];
    float c = (float)((endi - start) > 1 ? (endi - start) : 1);
    pooled[g * 64 + lane] = s / c;
}

// ---------------- classifier + log_softmax ----------------
__global__ void classify_kernel(const float* __restrict__ pooled, const float* __restrict__ cw,
                                const float* __restrict__ cb, float* __restrict__ out) {
    int g = threadIdx.x;
    if (g >= NUM_GRAPHS) return;
    float lg[NUM_CLASSES];
#pragma unroll
    for (int c = 0; c < NUM_CLASSES; ++c) lg[c] = cb[c];
    for (int d = 0; d < OUT_F; ++d) {
        float p = pooled[g * 64 + d];
#pragma unroll
        for (int c = 0; c < NUM_CLASSES; ++c) lg[c] += p * cw[d * NUM_CLASSES + c];
    }
    float m = lg[0];
#pragma unroll
    for (int c = 1; c < NUM_CLASSES; ++c) m = fmaxf(m, lg[c]);
    float s = 0.f;
#pragma unroll
    for (int c = 0; c < NUM_CLASSES; ++c) s += expf(lg[c] - m);
    float lse = m + logf(s);
#pragma unroll
    for (int c = 0; c < NUM_CLASSES; ++c) out[g * NUM_CLASSES + c] = lg[c] - lse;
}

extern "C" void kernel_launch(void* const* d_in, const int* in_sizes, int n_in,
                              void* d_out, int out_size, void* d_ws, size_t ws_size,
                              hipStream_t stream) {
    const float* x   = (const float*)d_in[0];
    const int*   ei  = (const int*)d_in[1];
    const float* ea  = (const float*)d_in[2];
    const int* batch = (const int*)d_in[3];
    const float* W0  = (const float*)d_in[4];
    const float* a0  = (const float*)d_in[5];
    const float* W1  = (const float*)d_in[6];
    const float* a1  = (const float*)d_in[7];
    const float* W2  = (const float*)d_in[8];
    // a2 (d_in[9]) unused: softmax over a single head is identically 1
    const float* cw  = (const float*)d_in[10];
    const float* cb  = (const float*)d_in[11];
    float* out = (float*)d_out;

    const int* srcp = ei;
    const int* dstp = ei + N_EDGES;

    char* ws = (char*)d_ws;
    size_t off = 0;
    auto alloc = [&](size_t bytes) -> char* {
        char* p = ws + off;
        off += (bytes + 255) & ~(size_t)255;
        return p;
    };
    float* Wh = (float*)alloc((size_t)N_NODES * 256 * 4);
    float* hA = (float*)alloc((size_t)N_NODES * 256 * 4);
    float* hB = (float*)alloc((size_t)N_NODES * 256 * 4);
    float* si = (float*)alloc((size_t)N_NODES * HEADS * 4);
    float* sj = (float*)alloc((size_t)N_NODES * HEADS * 4);
    float* se = (float*)alloc((size_t)N_EDGES * HEADS * 4);
    int* row_ptr = (int*)alloc((N_NODES + 1) * 4);
    int* cnt = (int*)alloc(N_NODES * 4);
    int* perm = (int*)alloc(N_EDGES * 4);
    float* pooled = (float*)alloc(NUM_GRAPHS * 64 * 4);
    float* h3 = hA;  // hA is free after layer-1 GEMM consumes it

    // CSR build (shared by all three layers)
    hipMemsetAsync(cnt, 0, N_NODES * 4, stream);
    count_kernel<<<(N_EDGES + 255) / 256, 256, 0, stream>>>(srcp, cnt);
    scan_kernel<<<1, 1024, 0, stream>>>(cnt, row_ptr);
    hipMemsetAsync(cnt, 0, N_NODES * 4, stream);
    scatter_kernel<<<(N_EDGES + 255) / 256, 256, 0, stream>>>(srcp, row_ptr, cnt, perm);

    dim3 ggrid((N_NODES + BM - 1) / BM, 256 / BN);
    dim3 ggrid2((N_NODES + BM - 1) / BM, 64 / BN);
    int nsb = (N_NODES * HEADS + 255) / 256;
    int esb = (N_EDGES + 255) / 256;
    int agb = (N_NODES + 3) / 4;

    // layer 0
    gemm_f32<<<ggrid, 256, 0, stream>>>(x, W0, Wh, N_NODES, 256, 256);
    node_scores<<<nsb, 256, 0, stream>>>(Wh, a0, si, sj);
    edge_scores<<<esb, 256, 0, stream>>>(ea, a0, se);
    edge_agg_concat<<<agb, 256, 0, stream>>>(Wh, si, sj, se, row_ptr, perm, dstp, hA);

    // layer 1
    gemm_f32<<<ggrid, 256, 0, stream>>>(hA, W1, Wh, N_NODES, 256, 256);
    node_scores<<<nsb, 256, 0, stream>>>(Wh, a1, si, sj);
    edge_scores<<<esb, 256, 0, stream>>>(ea, a1, se);
    edge_agg_concat<<<agb, 256, 0, stream>>>(Wh, si, sj, se, row_ptr, perm, dstp, hB);

    // layer 2 (single head, att == 1, mean over 1 head = identity, no activation)
    gemm_f32<<<ggrid2, 256, 0, stream>>>(hB, W2, Wh, N_NODES, 64, 256);
    edge_agg_single<<<agb, 256, 0, stream>>>(Wh, row_ptr, perm, dstp, h3);

    // pooling + classifier
    pool_kernel<<<NUM_GRAPHS, 64, 0, stream>>>(h3, batch, pooled);
    classify_kernel<<<1, 64, 0, stream>>>(pooled, cw, cb, out);
}

// Round 2
// 411.249 us; speedup vs baseline: 1.3222x; 1.3222x over previous
//
#include <hip/hip_runtime.h>
#include <hip/hip_bf16.h>
#include <math.h>

#define N_NODES 20000
#define N_EDGES 320000
#define IN_F 256
#define HID 64
#define HEADS 4
#define OUT_F 64
#define EDGE_F 16
#define NUM_CLASSES 10
#define NUM_GRAPHS 40
#define LRELU_ALPHA 0.2f

// ---------------- CSR build (edge list -> sorted-by-src permutation) ----------------
__global__ void count_kernel(const int* __restrict__ src, int* __restrict__ cnt) {
    int e = blockIdx.x * blockDim.x + threadIdx.x;
    if (e < N_EDGES) atomicAdd(&cnt[src[e]], 1);
}

// wave-shuffle inclusive scan, 1024-thread block, 20000 elements in 20 chunks
__global__ __launch_bounds__(1024) void scan_kernel(const int* __restrict__ cnt,
                                                    int* __restrict__ row_ptr) {
    __shared__ int wsum[16];
    __shared__ int carry_s;
    int t = threadIdx.x;
    int lane = t & 63, wave = t >> 6;
    if (t == 0) { carry_s = 0; row_ptr[0] = 0; }
    __syncthreads();
    for (int base = 0; base < N_NODES; base += 1024) {
        int idx = base + t;
        int x = (idx < N_NODES) ? cnt[idx] : 0;
        // wave-local inclusive prefix
#pragma unroll
        for (int off = 1; off < 64; off <<= 1) {
            int y = __shfl_up(x, off, 64);
            if (lane >= off) x += y;
        }
        if (lane == 63) wsum[wave] = x;
        __syncthreads();
        if (wave == 0 && lane < 16) {
            int s = wsum[lane];
#pragma unroll
            for (int off = 1; off < 16; off <<= 1) {
                int y = __shfl_up(s, off, 64);
                if (lane >= off) s += y;
            }
            wsum[lane] = s;
        }
        __syncthreads();
        int waveoff = (wave > 0) ? wsum[wave - 1] : 0;
        int carry = carry_s;
        if (idx < N_NODES) row_ptr[idx + 1] = x + waveoff + carry;
        __syncthreads();
        if (t == 0) carry_s = carry + wsum[15];
        __syncthreads();
    }
}

__global__ void scatter_kernel(const int* __restrict__ src, const int* __restrict__ row_ptr,
                               int* __restrict__ cursor, int* __restrict__ perm) {
    int e = blockIdx.x * blockDim.x + threadIdx.x;
    if (e < N_EDGES) {
        int s = src[e];
        int pos = row_ptr[s] + atomicAdd(&cursor[s], 1);
        perm[pos] = e;
    }
}

// ---------------- fp32 tiled GEMM: C[MxN] = A[MxK] * B[KxN] ----------------
#define BM 64
#define BN 64
#define BK 16
__global__ __launch_bounds__(256) void gemm_f32(const float* __restrict__ A,
                                                const float* __restrict__ B,
                                                float* __restrict__ C,
                                                int M, int N, int K) {
    __shared__ float As[BK][BM + 4];
    __shared__ float Bs[BK][BN];
    int tid = threadIdx.x;
    int tx = tid & 15, ty = tid >> 4;
    int bm = blockIdx.x * BM, bn = blockIdx.y * BN;
    float c[4][4] = {};
    int ar = tid >> 2, ac = (tid & 3) * 4;
    int br = tid >> 4, bc = (tid & 15) * 4;

    for (int k0 = 0; k0 < K; k0 += BK) {
        float4 av = make_float4(0.f, 0.f, 0.f, 0.f);
        if (bm + ar < M) av = *(const float4*)(A + (size_t)(bm + ar) * K + k0 + ac);
        As[ac + 0][ar] = av.x; As[ac + 1][ar] = av.y;
        As[ac + 2][ar] = av.z; As[ac + 3][ar] = av.w;
        float4 bv = *(const float4*)(B + (size_t)(k0 + br) * N + bn + bc);
        *(float4*)&Bs[br][bc] = bv;
        __syncthreads();
#pragma unroll
        for (int kk = 0; kk < BK; ++kk) {
            float4 a4 = *(const float4*)&As[kk][ty * 4];
            float4 b4 = *(const float4*)&Bs[kk][tx * 4];
            float a[4] = {a4.x, a4.y, a4.z, a4.w};
            float b[4] = {b4.x, b4.y, b4.z, b4.w};
#pragma unroll
            for (int i = 0; i < 4; ++i)
#pragma unroll
                for (int j = 0; j < 4; ++j) c[i][j] += a[i] * b[j];
        }
        __syncthreads();
    }
#pragma unroll
    for (int i = 0; i < 4; ++i) {
        int r = bm + ty * 4 + i;
        if (r < M) {
#pragma unroll
            for (int j = 0; j < 4; ++j) C[(size_t)r * N + bn + tx * 4 + j] = c[i][j];
        }
    }
}

// ---------------- per-node attention scores: s_i, s_j ----------------
__global__ void node_scores(const float* __restrict__ Wh, const float* __restrict__ a,
                            float* __restrict__ si, float* __restrict__ sj) {
    __shared__ float sa[HEADS * 144];
    int tid = threadIdx.x;
    for (int i = tid; i < HEADS * 144; i += blockDim.x) sa[i] = a[i];
    __syncthreads();
    int gid = blockIdx.x * blockDim.x + tid;
    if (gid >= N_NODES * HEADS) return;
    int h = gid & 3;
    const float* w = Wh + (size_t)(gid >> 2) * 256 + h * 64;
    const float* ai = sa + h * 144;
    const float* aj = ai + 64;
    float s0 = 0.f, s1 = 0.f;
#pragma unroll
    for (int d = 0; d < 64; d += 4) {
        float4 wv = *(const float4*)(w + d);
        s0 += wv.x * ai[d] + wv.y * ai[d + 1] + wv.z * ai[d + 2] + wv.w * ai[d + 3];
        s1 += wv.x * aj[d] + wv.y * aj[d + 1] + wv.z * aj[d + 2] + wv.w * aj[d + 3];
    }
    si[gid] = s0;
    sj[gid] = s1;
}

// ---------------- per-edge scores: s_e = edge_attr @ a_e^T ----------------
__global__ void edge_scores(const float* __restrict__ ea, const float* __restrict__ a,
                            float* __restrict__ se) {
    __shared__ float sae[HEADS * EDGE_F];
    int tid = threadIdx.x;
    if (tid < HEADS * EDGE_F) {
        int h = tid / EDGE_F, k = tid % EDGE_F;
        sae[tid] = a[h * 144 + 128 + k];
    }
    __syncthreads();
    int e = blockIdx.x * blockDim.x + tid;
    if (e >= N_EDGES) return;
    float x[16];
#pragma unroll
    for (int k = 0; k < 16; k += 4) {
        float4 v = *(const float4*)(ea + (size_t)e * 16 + k);
        x[k] = v.x; x[k + 1] = v.y; x[k + 2] = v.z; x[k + 3] = v.w;
    }
    float4 o;
    float* op = &o.x;
#pragma unroll
    for (int h = 0; h < HEADS; ++h) {
        float s = 0.f;
#pragma unroll
        for (int k = 0; k < 16; ++k) s += x[k] * sae[h * 16 + k];
        op[h] = s;
    }
    *(float4*)(se + (size_t)e * 4) = o;
}

// ---------------- edge aggregation, 4 heads, concat + ELU ----------------
__global__ __launch_bounds__(256) void edge_agg_concat(
    const float* __restrict__ Wh, const float* __restrict__ si, const float* __restrict__ sj,
    const float* __restrict__ se, const int* __restrict__ row_ptr, const int* __restrict__ perm,
    const int* __restrict__ dst, float* __restrict__ out) {
    int v = blockIdx.x * 4 + (threadIdx.x >> 6);
    if (v >= N_NODES) return;
    int lane = threadIdx.x & 63;
    float4 siv = *(const float4*)(si + (size_t)v * 4);
    float a0 = 0.f, a1 = 0.f, a2 = 0.f, a3 = 0.f;
    int end = row_ptr[v + 1];
    for (int i = row_ptr[v]; i < end; ++i) {
        int e = perm[i];
        int u = dst[e];
        float4 sjv = *(const float4*)(sj + (size_t)u * 4);
        float4 sev = *(const float4*)(se + (size_t)e * 4);
        float t0 = siv.x + sjv.x + sev.x;
        float t1 = siv.y + sjv.y + sev.y;
        float t2 = siv.z + sjv.z + sev.z;
        float t3 = siv.w + sjv.w + sev.w;
        t0 = t0 > 0.f ? t0 : LRELU_ALPHA * t0;
        t1 = t1 > 0.f ? t1 : LRELU_ALPHA * t1;
        t2 = t2 > 0.f ? t2 : LRELU_ALPHA * t2;
        t3 = t3 > 0.f ? t3 : LRELU_ALPHA * t3;
        float m = fmaxf(fmaxf(t0, t1), fmaxf(t2, t3));
        float p0 = __expf(t0 - m), p1 = __expf(t1 - m), p2 = __expf(t2 - m), p3 = __expf(t3 - m);
        float inv = 1.0f / (p0 + p1 + p2 + p3);
        const float* w = Wh + (size_t)u * 256 + lane;
        a0 += p0 * inv * w[0];
        a1 += p1 * inv * w[64];
        a2 += p2 * inv * w[128];
        a3 += p3 * inv * w[192];
    }
    float* o = out + (size_t)v * 256 + lane;
    o[0]   = a0 > 0.f ? a0 : __expf(a0) - 1.0f;
    o[64]  = a1 > 0.f ? a1 : __expf(a1) - 1.0f;
    o[128] = a2 > 0.f ? a2 : __expf(a2) - 1.0f;
    o[192] = a3 > 0.f ? a3 : __expf(a3) - 1.0f;
}

// ---------------- edge aggregation, single head (att == 1), no activation ----------------
__global__ __launch_bounds__(256) void edge_agg_single(
    const float* __restrict__ Wh, const int* __restrict__ row_ptr, const int* __restrict__ perm,
    const int* __restrict__ dst, float* __restrict__ out) {
    int v = blockIdx.x * 4 + (threadIdx.x >> 6);
    if (v >= N_NODES) return;
    int lane = threadIdx.x & 63;
    float acc = 0.f;
    int end = row_ptr[v + 1];
    for (int i = row_ptr[v]; i < end; ++i) {
        int u = dst[perm[i]];
        acc += Wh[(size_t)u * 64 + lane];
    }
    out[(size_t)v * 64 + lane] = acc;
}

// ---------------- mean pool per graph (batch sorted), 16 waves per graph ----------------
__global__ __launch_bounds__(1024) void pool_kernel(const float* __restrict__ h3,
                                                    const int* __restrict__ batch,
                                                    float* __restrict__ pooled) {
    int g = blockIdx.x;
    int lane = threadIdx.x & 63;
    int wave = threadIdx.x >> 6;  // 0..15
    int lo = 0, hi = N_NODES;
    while (lo < hi) { int mid = (lo + hi) >> 1; if (batch[mid] < g) lo = mid + 1; else hi = mid; }
    int start = lo;
    lo = start; hi = N_NODES;
    while (lo < hi) { int mid = (lo + hi) >> 1; if (batch[mid] < g + 1) lo = mid + 1; else hi = mid; }
    int endi = lo;
    float s = 0.f;
    for (int v = start + wave; v < endi; v += 16) s += h3[(size_t)v * 64 + lane];
    __shared__ float red[16][64];
    red[wave][lane] = s;
    __syncthreads();
    if (wave == 0) {
        float t = red[0][lane];
#pragma unroll
        for (int w = 1; w < 16; ++w) t += red[w][lane];
        float c = (float)((endi - start) > 1 ? (endi - start) : 1);
        pooled[g * 64 + lane] = t / c;
    }
}

// ---------------- classifier + log_softmax ----------------
__global__ void classify_kernel(const float* __restrict__ pooled, const float* __restrict__ cw,
                                const float* __restrict__ cb, float* __restrict__ out) {
    int g = threadIdx.x;
    if (g >= NUM_GRAPHS) return;
    float lg[NUM_CLASSES];
#pragma unroll
    for (int c = 0; c < NUM_CLASSES; ++c) lg[c] = cb[c];
    for (int d = 0; d < OUT_F; ++d) {
        float p = pooled[g * 64 + d];
#pragma unroll
        for (int c = 0; c < NUM_CLASSES; ++c) lg[c] += p * cw[d * NUM_CLASSES + c];
    }
    float m = lg[0];
#pragma unroll
    for (int c = 1; c < NUM_CLASSES; ++c) m = fmaxf(m, lg[c]);
    float s = 0.f;
#pragma unroll
    for (int c = 0; c < NUM_CLASSES; ++c) s += expf(lg[c] - m);
    float lse = m + logf(s);
#pragma unroll
    for (int c = 0; c < NUM_CLASSES; ++c) out[g * NUM_CLASSES + c] = lg[c] - lse;
}

extern "C" void kernel_launch(void* const* d_in, const int* in_sizes, int n_in,
                              void* d_out, int out_size, void* d_ws, size_t ws_size,
                              hipStream_t stream) {
    const float* x   = (const float*)d_in[0];
    const int*   ei  = (const int*)d_in[1];
    const float* ea  = (const float*)d_in[2];
    const int* batch = (const int*)d_in[3];
    const float* W0  = (const float*)d_in[4];
    const float* a0  = (const float*)d_in[5];
    const float* W1  = (const float*)d_in[6];
    const float* a1  = (const float*)d_in[7];
    const float* W2  = (const float*)d_in[8];
    const float* cw  = (const float*)d_in[10];
    const float* cb  = (const float*)d_in[11];
    float* out = (float*)d_out;

    const int* srcp = ei;
    const int* dstp = ei + N_EDGES;

    char* ws = (char*)d_ws;
    size_t off = 0;
    auto alloc = [&](size_t bytes) -> char* {
        char* p = ws + off;
        off += (bytes + 255) & ~(size_t)255;
        return p;
    };
    float* Wh = (float*)alloc((size_t)N_NODES * 256 * 4);
    float* hA = (float*)alloc((size_t)N_NODES * 256 * 4);
    float* hB = (float*)alloc((size_t)N_NODES * 256 * 4);
    float* si = (float*)alloc((size_t)N_NODES * HEADS * 4);
    float* sj = (float*)alloc((size_t)N_NODES * HEADS * 4);
    float* se = (float*)alloc((size_t)N_EDGES * HEADS * 4);
    int* row_ptr = (int*)alloc((N_NODES + 1) * 4);
    int* cnt = (int*)alloc(N_NODES * 4);
    int* perm = (int*)alloc(N_EDGES * 4);
    float* pooled = (float*)alloc(NUM_GRAPHS * 64 * 4);
    float* h3 = hA;

    // CSR build (shared by all three layers)
    hipMemsetAsync(cnt, 0, N_NODES * 4, stream);
    count_kernel<<<(N_EDGES + 255) / 256, 256, 0, stream>>>(srcp, cnt);
    scan_kernel<<<1, 1024, 0, stream>>>(cnt, row_ptr);
    hipMemsetAsync(cnt, 0, N_NODES * 4, stream);
    scatter_kernel<<<(N_EDGES + 255) / 256, 256, 0, stream>>>(srcp, row_ptr, cnt, perm);

    dim3 ggrid((N_NODES + BM - 1) / BM, 256 / BN);
    dim3 ggrid2((N_NODES + BM - 1) / BM, 64 / BN);
    int nsb = (N_NODES * HEADS + 255) / 256;
    int esb = (N_EDGES + 255) / 256;
    int agb = (N_NODES + 3) / 4;

    // layer 0
    gemm_f32<<<ggrid, 256, 0, stream>>>(x, W0, Wh, N_NODES, 256, 256);
    node_scores<<<nsb, 256, 0, stream>>>(Wh, a0, si, sj);
    edge_scores<<<esb, 256, 0, stream>>>(ea, a0, se);
    edge_agg_concat<<<agb, 256, 0, stream>>>(Wh, si, sj, se, row_ptr, perm, dstp, hA);

    // layer 1
    gemm_f32<<<ggrid, 256, 0, stream>>>(hA, W1, Wh, N_NODES, 256, 256);
    node_scores<<<nsb, 256, 0, stream>>>(Wh, a1, si, sj);
    edge_scores<<<esb, 256, 0, stream>>>(ea, a1, se);
    edge_agg_concat<<<agb, 256, 0, stream>>>(Wh, si, sj, se, row_ptr, perm, dstp, hB);

    // layer 2 (single head, att == 1, mean over 1 head = identity)
    gemm_f32<<<ggrid2, 256, 0, stream>>>(hB, W2, Wh, N_NODES, 64, 256);
    edge_agg_single<<<agb, 256, 0, stream>>>(Wh, row_ptr, perm, dstp, h3);

    // pooling + classifier
    pool_kernel<<<NUM_GRAPHS, 1024, 0, stream>>>(h3, batch, pooled);
    classify_kernel<<<1, 64, 0, stream>>>(pooled, cw, cb, out);
}

// Round 3
// 253.561 us; speedup vs baseline: 2.1445x; 1.6219x over previous
//
#include <hip/hip_runtime.h>
#include <hip/hip_bf16.h>
#include <math.h>

#define N_NODES 20000
#define N_EDGES 320000
#define IN_F 256
#define HID 64
#define HEADS 4
#define OUT_F 64
#define EDGE_F 16
#define NUM_CLASSES 10
#define NUM_GRAPHS 40
#define LRELU_ALPHA 0.2f

typedef short bf16x8 __attribute__((ext_vector_type(8)));
typedef float f32x4 __attribute__((ext_vector_type(4)));

static __device__ __forceinline__ float bf2f(unsigned short u) {
    union { unsigned int i; float f; } v; v.i = ((unsigned int)u) << 16; return v.f;
}
static __device__ __forceinline__ unsigned short f2bf(float f) {
    union { float f; unsigned int i; } v; v.f = f;
    unsigned int r = v.i + 0x7FFF + ((v.i >> 16) & 1);
    return (unsigned short)(r >> 16);
}
static __device__ __forceinline__ float eluf(float a) {
    return a > 0.f ? a : __expf(a) - 1.0f;
}

// ---------------- fp32 -> bf16 convert ----------------
__global__ void f2bf_kernel(const float* __restrict__ in, unsigned short* __restrict__ out, int n4) {
    int i = blockIdx.x * blockDim.x + threadIdx.x;
    if (i >= n4) return;
    float4 v = ((const float4*)in)[i];
    ushort4 o;
    o.x = f2bf(v.x); o.y = f2bf(v.y); o.z = f2bf(v.z); o.w = f2bf(v.w);
    ((ushort4*)out)[i] = o;
}

// ---------------- CSR build ----------------
__global__ void count_kernel(const int* __restrict__ src, int* __restrict__ cnt) {
    int e = blockIdx.x * blockDim.x + threadIdx.x;
    if (e < N_EDGES) atomicAdd(&cnt[src[e]], 1);
}

__global__ __launch_bounds__(1024) void scan_kernel(const int* __restrict__ cnt,
                                                    int* __restrict__ row_ptr) {
    __shared__ int wsum[16];
    __shared__ int carry_s;
    int t = threadIdx.x;
    int lane = t & 63, wave = t >> 6;
    if (t == 0) { carry_s = 0; row_ptr[0] = 0; }
    __syncthreads();
    for (int base = 0; base < N_NODES; base += 1024) {
        int idx = base + t;
        int x = (idx < N_NODES) ? cnt[idx] : 0;
#pragma unroll
        for (int off = 1; off < 64; off <<= 1) {
            int y = __shfl_up(x, off, 64);
            if (lane >= off) x += y;
        }
        if (lane == 63) wsum[wave] = x;
        __syncthreads();
        if (wave == 0 && lane < 16) {
            int s = wsum[lane];
#pragma unroll
            for (int off = 1; off < 16; off <<= 1) {
                int y = __shfl_up(s, off, 64);
                if (lane >= off) s += y;
            }
            wsum[lane] = s;
        }
        __syncthreads();
        int waveoff = (wave > 0) ? wsum[wave - 1] : 0;
        int carry = carry_s;
        if (idx < N_NODES) row_ptr[idx + 1] = x + waveoff + carry;
        __syncthreads();
        if (t == 0) carry_s = carry + wsum[15];
        __syncthreads();
    }
}

__global__ void scatter_kernel(const int* __restrict__ src, const int* __restrict__ dst,
                               const int* __restrict__ row_ptr, int* __restrict__ cursor,
                               int* __restrict__ perm, int* __restrict__ srcp,
                               int* __restrict__ dstp) {
    int e = blockIdx.x * blockDim.x + threadIdx.x;
    if (e < N_EDGES) {
        int s = src[e];
        int pos = row_ptr[s] + atomicAdd(&cursor[s], 1);
        perm[pos] = e;
        srcp[pos] = s;
        dstp[pos] = dst[e];
    }
}

// ---------------- bf16 MFMA GEMM: C[MxN] = A[MxK] * B[KxN] ----------------
// A,B,C bf16 (fp32 accumulate). K % 32 == 0, N % 64 == 0, M guarded.
__global__ __launch_bounds__(256) void gemm_bf16(const unsigned short* __restrict__ A,
                                                 const unsigned short* __restrict__ B,
                                                 unsigned short* __restrict__ C,
                                                 int M, int N, int K) {
    __shared__ unsigned short As[64][40];   // [row][k], pad 32->40 keeps 16B align, spreads banks
    __shared__ unsigned short Bs[64][40];   // [n][k] (transposed)
    __shared__ unsigned short Cs[64][72];   // epilogue staging
    int tid = threadIdx.x;
    int bm = blockIdx.x * 64, bn = blockIdx.y * 64;
    int w = tid >> 6, l = tid & 63;
    int wr = (w >> 1) * 32, wc = (w & 1) * 32;   // wave's 32x32 quadrant
    int lr = l & 15, lk = (l >> 4) * 8;
    f32x4 acc[2][2] = {};
    int ar = tid >> 2, akc = (tid & 3) * 8;      // A stage: row, k-chunk
    int bk = tid >> 3, bnc = (tid & 7) * 8;      // B stage: k, n-chunk

    for (int k0 = 0; k0 < K; k0 += 32) {
        bf16x8 av = {};
        if (bm + ar < M) av = *(const bf16x8*)(A + (size_t)(bm + ar) * K + k0 + akc);
        *(bf16x8*)&As[ar][akc] = av;
        bf16x8 bv = *(const bf16x8*)(B + (size_t)(k0 + bk) * N + bn + bnc);
#pragma unroll
        for (int j = 0; j < 8; ++j) Bs[bnc + j][bk] = (unsigned short)bv[j];
        __syncthreads();
        bf16x8 a0 = *(const bf16x8*)&As[wr + lr][lk];
        bf16x8 a1 = *(const bf16x8*)&As[wr + 16 + lr][lk];
        bf16x8 b0 = *(const bf16x8*)&Bs[wc + lr][lk];
        bf16x8 b1 = *(const bf16x8*)&Bs[wc + 16 + lr][lk];
        acc[0][0] = __builtin_amdgcn_mfma_f32_16x16x32_bf16(a0, b0, acc[0][0], 0, 0, 0);
        acc[0][1] = __builtin_amdgcn_mfma_f32_16x16x32_bf16(a0, b1, acc[0][1], 0, 0, 0);
        acc[1][0] = __builtin_amdgcn_mfma_f32_16x16x32_bf16(a1, b0, acc[1][0], 0, 0, 0);
        acc[1][1] = __builtin_amdgcn_mfma_f32_16x16x32_bf16(a1, b1, acc[1][1], 0, 0, 0);
        __syncthreads();
    }
    // D layout: col = lane&15, row = (lane>>4)*4 + reg  [guide-verified m89/m91]
#pragma unroll
    for (int i = 0; i < 2; ++i)
#pragma unroll
        for (int j = 0; j < 2; ++j)
#pragma unroll
            for (int r = 0; r < 4; ++r)
                Cs[wr + i * 16 + (l >> 4) * 4 + r][wc + j * 16 + (l & 15)] = f2bf(acc[i][j][r]);
    __syncthreads();
    int row = tid >> 3, cc = (tid & 7) * 8;
#pragma unroll
    for (int p = 0; p < 2; ++p, row += 32) {
        if (bm + row < M) {
            bf16x8 o = *(const bf16x8*)&Cs[row][cc];
            *(bf16x8*)(C + (size_t)(bm + row) * N + bn + cc) = o;
        }
    }
}

// ---------------- per-node attention scores: s_i, s_j (bf16 Wh) ----------------
__global__ void node_scores(const unsigned short* __restrict__ Wh, const float* __restrict__ a,
                            float* __restrict__ si, float* __restrict__ sj) {
    __shared__ float sa[HEADS * 144];
    int tid = threadIdx.x;
    for (int i = tid; i < HEADS * 144; i += blockDim.x) sa[i] = a[i];
    __syncthreads();
    int gid = blockIdx.x * blockDim.x + tid;
    if (gid >= N_NODES * HEADS) return;
    int h = gid & 3;
    const unsigned short* w = Wh + (size_t)(gid >> 2) * 256 + h * 64;
    const float* ai = sa + h * 144;
    const float* aj = ai + 64;
    float s0 = 0.f, s1 = 0.f;
#pragma unroll
    for (int d = 0; d < 64; d += 8) {
        bf16x8 wv = *(const bf16x8*)(w + d);
#pragma unroll
        for (int j = 0; j < 8; ++j) {
            float f = bf2f((unsigned short)wv[j]);
            s0 += f * ai[d + j];
            s1 += f * aj[d + j];
        }
    }
    si[gid] = s0;
    sj[gid] = s1;
}

// ---------------- per-edge attention (CSR order): leaky-relu + head-softmax ----------------
__global__ void att_kernel(const int* __restrict__ perm, const int* __restrict__ srcp,
                           const int* __restrict__ dstp, const float* __restrict__ ea,
                           const float* __restrict__ a, const float* __restrict__ si,
                           const float* __restrict__ sj, float* __restrict__ attp) {
    __shared__ float ae[HEADS][EDGE_F];
    int tid = threadIdx.x;
    if (tid < HEADS * EDGE_F) ae[tid >> 4][tid & 15] = a[(tid >> 4) * 144 + 128 + (tid & 15)];
    __syncthreads();
    int i = blockIdx.x * blockDim.x + tid;
    if (i >= N_EDGES) return;
    int e = perm[i], s = srcp[i], u = dstp[i];
    float4 siv = ((const float4*)si)[s];
    float4 sjv = ((const float4*)sj)[u];
    float x[16];
#pragma unroll
    for (int k = 0; k < 16; k += 4) {
        float4 v = *(const float4*)(ea + (size_t)e * 16 + k);
        x[k] = v.x; x[k + 1] = v.y; x[k + 2] = v.z; x[k + 3] = v.w;
    }
    float se0 = 0.f, se1 = 0.f, se2 = 0.f, se3 = 0.f;
#pragma unroll
    for (int k = 0; k < 16; ++k) {
        se0 += x[k] * ae[0][k];
        se1 += x[k] * ae[1][k];
        se2 += x[k] * ae[2][k];
        se3 += x[k] * ae[3][k];
    }
    float t0 = siv.x + sjv.x + se0;
    float t1 = siv.y + sjv.y + se1;
    float t2 = siv.z + sjv.z + se2;
    float t3 = siv.w + sjv.w + se3;
    t0 = t0 > 0.f ? t0 : LRELU_ALPHA * t0;
    t1 = t1 > 0.f ? t1 : LRELU_ALPHA * t1;
    t2 = t2 > 0.f ? t2 : LRELU_ALPHA * t2;
    t3 = t3 > 0.f ? t3 : LRELU_ALPHA * t3;
    float m = fmaxf(fmaxf(t0, t1), fmaxf(t2, t3));
    float p0 = __expf(t0 - m), p1 = __expf(t1 - m), p2 = __expf(t2 - m), p3 = __expf(t3 - m);
    float inv = 1.0f / (p0 + p1 + p2 + p3);
    float4 o = make_float4(p0 * inv, p1 * inv, p2 * inv, p3 * inv);
    ((float4*)attp)[i] = o;
}

// ---------------- edge aggregation, 4 heads, concat + ELU (bf16 in/out) ----------------
// one wave per node; lane l gathers ushort4 = 4 dims of head (l>>4); whole row = one 512B txn
__global__ __launch_bounds__(256) void edge_agg_concat(
    const unsigned short* __restrict__ Whb, const float* __restrict__ attp,
    const int* __restrict__ row_ptr, const int* __restrict__ dstp,
    unsigned short* __restrict__ out) {
    int v = blockIdx.x * 4 + (threadIdx.x >> 6);
    if (v >= N_NODES) return;
    int l = threadIdx.x & 63;
    int h = l >> 4;
    int beg = row_ptr[v], end = row_ptr[v + 1];
    float a0 = 0.f, a1 = 0.f, a2 = 0.f, a3 = 0.f;
    int u_n = (beg < end) ? dstp[beg] : 0;
    float at_n = (beg < end) ? attp[(size_t)beg * 4 + h] : 0.f;
    for (int i = beg; i < end; ++i) {
        int u = u_n;
        float at = at_n;
        if (i + 1 < end) {
            u_n = dstp[i + 1];
            at_n = attp[(size_t)(i + 1) * 4 + h];
        }
        ushort4 w4 = ((const ushort4*)(Whb + (size_t)u * 256))[l];
        a0 += at * bf2f(w4.x);
        a1 += at * bf2f(w4.y);
        a2 += at * bf2f(w4.z);
        a3 += at * bf2f(w4.w);
    }
    ushort4 o;
    o.x = f2bf(eluf(a0)); o.y = f2bf(eluf(a1)); o.z = f2bf(eluf(a2)); o.w = f2bf(eluf(a3));
    ((ushort4*)(out + (size_t)v * 256))[l] = o;
}

// ---------------- edge aggregation, single head, fp32 out ----------------
__global__ __launch_bounds__(256) void edge_agg_single(
    const unsigned short* __restrict__ Whb, const int* __restrict__ row_ptr,
    const int* __restrict__ dstp, float* __restrict__ out) {
    int v = blockIdx.x * 4 + (threadIdx.x >> 6);
    if (v >= N_NODES) return;
    int l = threadIdx.x & 63;
    int beg = row_ptr[v], end = row_ptr[v + 1];
    float acc = 0.f;
    int u_n = (beg < end) ? dstp[beg] : 0;
    for (int i = beg; i < end; ++i) {
        int u = u_n;
        if (i + 1 < end) u_n = dstp[i + 1];
        acc += bf2f(Whb[(size_t)u * 64 + l]);
    }
    out[(size_t)v * 64 + l] = acc;
}

// ---------------- mean pool per graph (batch sorted), 16 waves per graph ----------------
__global__ __launch_bounds__(1024) void pool_kernel(const float* __restrict__ h3,
                                                    const int* __restrict__ batch,
                                                    float* __restrict__ pooled) {
    int g = blockIdx.x;
    int lane = threadIdx.x & 63;
    int wave = threadIdx.x >> 6;
    int lo = 0, hi = N_NODES;
    while (lo < hi) { int mid = (lo + hi) >> 1; if (batch[mid] < g) lo = mid + 1; else hi = mid; }
    int start = lo;
    lo = start; hi = N_NODES;
    while (lo < hi) { int mid = (lo + hi) >> 1; if (batch[mid] < g + 1) lo = mid + 1; else hi = mid; }
    int endi = lo;
    float s = 0.f;
    for (int v = start + wave; v < endi; v += 16) s += h3[(size_t)v * 64 + lane];
    __shared__ float red[16][64];
    red[wave][lane] = s;
    __syncthreads();
    if (wave == 0) {
        float t = red[0][lane];
#pragma unroll
        for (int w = 1; w < 16; ++w) t += red[w][lane];
        float c = (float)((endi - start) > 1 ? (endi - start) : 1);
        pooled[g * 64 + lane] = t / c;
    }
}

// ---------------- classifier + log_softmax ----------------
__global__ void classify_kernel(const float* __restrict__ pooled, const float* __restrict__ cw,
                                const float* __restrict__ cb, float* __restrict__ out) {
    int g = threadIdx.x;
    if (g >= NUM_GRAPHS) return;
    float lg[NUM_CLASSES];
#pragma unroll
    for (int c = 0; c < NUM_CLASSES; ++c) lg[c] = cb[c];
    for (int d = 0; d < OUT_F; ++d) {
        float p = pooled[g * 64 + d];
#pragma unroll
        for (int c = 0; c < NUM_CLASSES; ++c) lg[c] += p * cw[d * NUM_CLASSES + c];
    }
    float m = lg[0];
#pragma unroll
    for (int c = 1; c < NUM_CLASSES; ++c) m = fmaxf(m, lg[c]);
    float s = 0.f;
#pragma unroll
    for (int c = 0; c < NUM_CLASSES; ++c) s += expf(lg[c] - m);
    float lse = m + logf(s);
#pragma unroll
    for (int c = 0; c < NUM_CLASSES; ++c) out[g * NUM_CLASSES + c] = lg[c] - lse;
}

extern "C" void kernel_launch(void* const* d_in, const int* in_sizes, int n_in,
                              void* d_out, int out_size, void* d_ws, size_t ws_size,
                              hipStream_t stream) {
    const float* x   = (const float*)d_in[0];
    const int*   ei  = (const int*)d_in[1];
    const float* ea  = (const float*)d_in[2];
    const int* batch = (const int*)d_in[3];
    const float* W0  = (const float*)d_in[4];
    const float* a0  = (const float*)d_in[5];
    const float* W1  = (const float*)d_in[6];
    const float* a1  = (const float*)d_in[7];
    const float* W2  = (const float*)d_in[8];
    const float* cw  = (const float*)d_in[10];
    const float* cb  = (const float*)d_in[11];
    float* out = (float*)d_out;

    const int* srcg = ei;
    const int* dstg = ei + N_EDGES;

    char* ws = (char*)d_ws;
    size_t off = 0;
    auto alloc = [&](size_t bytes) -> char* {
        char* p = ws + off;
        off += (bytes + 255) & ~(size_t)255;
        return p;
    };
    unsigned short* xb   = (unsigned short*)alloc((size_t)N_NODES * 256 * 2);
    unsigned short* W0b  = (unsigned short*)alloc(256 * 256 * 2);
    unsigned short* W1b  = (unsigned short*)alloc(256 * 256 * 2);
    unsigned short* W2b  = (unsigned short*)alloc(256 * 64 * 2);
    unsigned short* Whb  = (unsigned short*)alloc((size_t)N_NODES * 256 * 2);
    unsigned short* hAb  = (unsigned short*)alloc((size_t)N_NODES * 256 * 2);
    unsigned short* hBb  = (unsigned short*)alloc((size_t)N_NODES * 256 * 2);
    unsigned short* Wh2b = (unsigned short*)alloc((size_t)N_NODES * 64 * 2);
    float* si   = (float*)alloc((size_t)N_NODES * HEADS * 4);
    float* sj   = (float*)alloc((size_t)N_NODES * HEADS * 4);
    float* attp = (float*)alloc((size_t)N_EDGES * HEADS * 4);
    int* row_ptr = (int*)alloc((N_NODES + 1) * 4);
    int* cnt  = (int*)alloc(N_NODES * 4);
    int* perm = (int*)alloc(N_EDGES * 4);
    int* srcp = (int*)alloc(N_EDGES * 4);
    int* dstp = (int*)alloc(N_EDGES * 4);
    float* h3 = (float*)alloc((size_t)N_NODES * 64 * 4);
    float* pooled = (float*)alloc(NUM_GRAPHS * 64 * 4);

    // dtype converts
    f2bf_kernel<<<(N_NODES * 256 / 4 + 255) / 256, 256, 0, stream>>>(x, xb, N_NODES * 256 / 4);
    f2bf_kernel<<<(256 * 256 / 4 + 255) / 256, 256, 0, stream>>>(W0, W0b, 256 * 256 / 4);
    f2bf_kernel<<<(256 * 256 / 4 + 255) / 256, 256, 0, stream>>>(W1, W1b, 256 * 256 / 4);
    f2bf_kernel<<<(256 * 64 / 4 + 255) / 256, 256, 0, stream>>>(W2, W2b, 256 * 64 / 4);

    // CSR build (shared by all three layers)
    hipMemsetAsync(cnt, 0, N_NODES * 4, stream);
    count_kernel<<<(N_EDGES + 255) / 256, 256, 0, stream>>>(srcg, cnt);
    scan_kernel<<<1, 1024, 0, stream>>>(cnt, row_ptr);
    hipMemsetAsync(cnt, 0, N_NODES * 4, stream);
    scatter_kernel<<<(N_EDGES + 255) / 256, 256, 0, stream>>>(srcg, dstg, row_ptr, cnt, perm, srcp, dstp);

    dim3 ggrid((N_NODES + 63) / 64, 4);
    dim3 ggrid2((N_NODES + 63) / 64, 1);
    int nsb = (N_NODES * HEADS + 255) / 256;
    int atb = (N_EDGES + 255) / 256;
    int agb = (N_NODES + 3) / 4;

    // layer 0
    gemm_bf16<<<ggrid, 256, 0, stream>>>(xb, W0b, Whb, N_NODES, 256, 256);
    node_scores<<<nsb, 256, 0, stream>>>(Whb, a0, si, sj);
    att_kernel<<<atb, 256, 0, stream>>>(perm, srcp, dstp, ea, a0, si, sj, attp);
    edge_agg_concat<<<agb, 256, 0, stream>>>(Whb, attp, row_ptr, dstp, hAb);

    // layer 1
    gemm_bf16<<<ggrid, 256, 0, stream>>>(hAb, W1b, Whb, N_NODES, 256, 256);
    node_scores<<<nsb, 256, 0, stream>>>(Whb, a1, si, sj);
    att_kernel<<<atb, 256, 0, stream>>>(perm, srcp, dstp, ea, a1, si, sj, attp);
    edge_agg_concat<<<agb, 256, 0, stream>>>(Whb, attp, row_ptr, dstp, hBb);

    // layer 2 (single head, att == 1, mean over 1 head = identity)
    gemm_bf16<<<ggrid2, 256, 0, stream>>>(hBb, W2b, Wh2b, N_NODES, 64, 256);
    edge_agg_single<<<agb, 256, 0, stream>>>(Wh2b, row_ptr, dstp, h3);

    // pooling + classifier
    pool_kernel<<<NUM_GRAPHS, 1024, 0, stream>>>(h3, batch, pooled);
    classify_kernel<<<1, 64, 0, stream>>>(pooled, cw, cb, out);
}

// Round 4
// 225.767 us; speedup vs baseline: 2.4086x; 1.1231x over previous
//
#include <hip/hip_runtime.h>
#include <hip/hip_bf16.h>
#include <math.h>

#define N_NODES 20000
#define N_EDGES 320000
#define IN_F 256
#define HID 64
#define HEADS 4
#define OUT_F 64
#define EDGE_F 16
#define NUM_CLASSES 10
#define NUM_GRAPHS 40
#define LRELU_ALPHA 0.2f

typedef short bf16x8 __attribute__((ext_vector_type(8)));
typedef unsigned short u16x8 __attribute__((ext_vector_type(8)));
typedef float f32x4 __attribute__((ext_vector_type(4)));

static __device__ __forceinline__ float bf2f(unsigned short u) {
    union { unsigned int i; float f; } v; v.i = ((unsigned int)u) << 16; return v.f;
}
static __device__ __forceinline__ unsigned short f2bf(float f) {
    union { float f; unsigned int i; } v; v.f = f;
    unsigned int r = v.i + 0x7FFF + ((v.i >> 16) & 1);
    return (unsigned short)(r >> 16);
}
static __device__ __forceinline__ float eluf(float a) {
    return a > 0.f ? a : __expf(a) - 1.0f;
}

// ---------------- fp32 -> bf16 convert (weights only) ----------------
__global__ void f2bf_kernel(const float* __restrict__ in, unsigned short* __restrict__ out, int n4) {
    int i = blockIdx.x * blockDim.x + threadIdx.x;
    if (i >= n4) return;
    float4 v = ((const float4*)in)[i];
    ushort4 o;
    o.x = f2bf(v.x); o.y = f2bf(v.y); o.z = f2bf(v.z); o.w = f2bf(v.w);
    ((ushort4*)out)[i] = o;
}

// ---------------- CSR build ----------------
__global__ void count_kernel(const int* __restrict__ src, int* __restrict__ cnt) {
    int e = blockIdx.x * blockDim.x + threadIdx.x;
    if (e < N_EDGES) atomicAdd(&cnt[src[e]], 1);
}

__global__ __launch_bounds__(1024) void scan_kernel(const int* __restrict__ cnt,
                                                    int* __restrict__ row_ptr) {
    __shared__ int wsum[16];
    __shared__ int carry_s;
    int t = threadIdx.x;
    int lane = t & 63, wave = t >> 6;
    if (t == 0) { carry_s = 0; row_ptr[0] = 0; }
    __syncthreads();
    for (int base = 0; base < N_NODES; base += 1024) {
        int idx = base + t;
        int x = (idx < N_NODES) ? cnt[idx] : 0;
#pragma unroll
        for (int off = 1; off < 64; off <<= 1) {
            int y = __shfl_up(x, off, 64);
            if (lane >= off) x += y;
        }
        if (lane == 63) wsum[wave] = x;
        __syncthreads();
        if (wave == 0 && lane < 16) {
            int s = wsum[lane];
#pragma unroll
            for (int off = 1; off < 16; off <<= 1) {
                int y = __shfl_up(s, off, 64);
                if (lane >= off) s += y;
            }
            wsum[lane] = s;
        }
        __syncthreads();
        int waveoff = (wave > 0) ? wsum[wave - 1] : 0;
        int carry = carry_s;
        if (idx < N_NODES) row_ptr[idx + 1] = x + waveoff + carry;
        __syncthreads();
        if (t == 0) carry_s = carry + wsum[15];
        __syncthreads();
    }
}

// scatter: build CSR-ordered src/dst AND permute edge_attr rows into CSR order
__global__ void scatter_kernel(const int* __restrict__ src, const int* __restrict__ dst,
                               const float* __restrict__ ea, const int* __restrict__ row_ptr,
                               int* __restrict__ cursor, int* __restrict__ srcp,
                               int* __restrict__ dstp, float* __restrict__ eap) {
    int e = blockIdx.x * blockDim.x + threadIdx.x;
    if (e < N_EDGES) {
        int s = src[e];
        int pos = row_ptr[s] + atomicAdd(&cursor[s], 1);
        srcp[pos] = s;
        dstp[pos] = dst[e];
#pragma unroll
        for (int k = 0; k < 4; ++k)
            ((float4*)(eap + (size_t)pos * 16))[k] = ((const float4*)(ea + (size_t)e * 16))[k];
    }
}

// ---------------- bf16 MFMA GEMM: C[MxN] = A[MxK] * B[KxN] ----------------
// A fp32 or bf16 (template), B/C bf16, fp32 accumulate. K%32==0, N%64==0, M guarded.
template <bool AF32>
__global__ __launch_bounds__(256) void gemm_bf16(const void* __restrict__ Aptr,
                                                 const unsigned short* __restrict__ B,
                                                 unsigned short* __restrict__ C,
                                                 int M, int N, int K) {
    __shared__ unsigned short As[64][40];
    __shared__ unsigned short Bs[64][40];   // [n][k] (transposed)
    __shared__ unsigned short Cs[64][72];
    int tid = threadIdx.x;
    int bm = blockIdx.x * 64, bn = blockIdx.y * 64;
    int w = tid >> 6, l = tid & 63;
    int wr = (w >> 1) * 32, wc = (w & 1) * 32;
    int lr = l & 15, lk = (l >> 4) * 8;
    f32x4 acc[2][2] = {};
    int ar = tid >> 2, akc = (tid & 3) * 8;
    int bk = tid >> 3, bn8 = tid & 7, bnc = bn8 * 8;

    for (int k0 = 0; k0 < K; k0 += 32) {
        bf16x8 av = {};
        if (bm + ar < M) {
            if constexpr (AF32) {
                const float* Af = (const float*)Aptr + (size_t)(bm + ar) * K + k0 + akc;
                float4 f0 = *(const float4*)Af;
                float4 f1 = *(const float4*)(Af + 4);
                av[0] = (short)f2bf(f0.x); av[1] = (short)f2bf(f0.y);
                av[2] = (short)f2bf(f0.z); av[3] = (short)f2bf(f0.w);
                av[4] = (short)f2bf(f1.x); av[5] = (short)f2bf(f1.y);
                av[6] = (short)f2bf(f1.z); av[7] = (short)f2bf(f1.w);
            } else {
                av = *(const bf16x8*)((const unsigned short*)Aptr + (size_t)(bm + ar) * K + k0 + akc);
            }
        }
        *(bf16x8*)&As[ar][akc] = av;
        bf16x8 bv = *(const bf16x8*)(B + (size_t)(k0 + bk) * N + bn + bnc);
#pragma unroll
        for (int j = 0; j < 8; ++j) {
            int jj = (j + bn8) & 7;  // rotate write order: 8-way bank conflict -> ~2-way
            Bs[bnc + jj][bk] = (unsigned short)bv[jj];
        }
        __syncthreads();
        bf16x8 a0 = *(const bf16x8*)&As[wr + lr][lk];
        bf16x8 a1 = *(const bf16x8*)&As[wr + 16 + lr][lk];
        bf16x8 b0 = *(const bf16x8*)&Bs[wc + lr][lk];
        bf16x8 b1 = *(const bf16x8*)&Bs[wc + 16 + lr][lk];
        acc[0][0] = __builtin_amdgcn_mfma_f32_16x16x32_bf16(a0, b0, acc[0][0], 0, 0, 0);
        acc[0][1] = __builtin_amdgcn_mfma_f32_16x16x32_bf16(a0, b1, acc[0][1], 0, 0, 0);
        acc[1][0] = __builtin_amdgcn_mfma_f32_16x16x32_bf16(a1, b0, acc[1][0], 0, 0, 0);
        acc[1][1] = __builtin_amdgcn_mfma_f32_16x16x32_bf16(a1, b1, acc[1][1], 0, 0, 0);
        __syncthreads();
    }
    // D layout: col = lane&15, row = (lane>>4)*4 + reg
#pragma unroll
    for (int i = 0; i < 2; ++i)
#pragma unroll
        for (int j = 0; j < 2; ++j)
#pragma unroll
            for (int r = 0; r < 4; ++r)
                Cs[wr + i * 16 + (l >> 4) * 4 + r][wc + j * 16 + (l & 15)] = f2bf(acc[i][j][r]);
    __syncthreads();
    int row = tid >> 3, cc = (tid & 7) * 8;
#pragma unroll
    for (int p = 0; p < 2; ++p, row += 32) {
        if (bm + row < M) {
            bf16x8 o = *(const bf16x8*)&Cs[row][cc];
            *(bf16x8*)(C + (size_t)(bm + row) * N + bn + cc) = o;
        }
    }
}

// ---------------- per-node attention scores: s_i, s_j (bf16 Wh) ----------------
__global__ void node_scores(const unsigned short* __restrict__ Wh, const float* __restrict__ a,
                            float* __restrict__ si, float* __restrict__ sj) {
    __shared__ float sa[HEADS * 144];
    int tid = threadIdx.x;
    for (int i = tid; i < HEADS * 144; i += blockDim.x) sa[i] = a[i];
    __syncthreads();
    int gid = blockIdx.x * blockDim.x + tid;
    if (gid >= N_NODES * HEADS) return;
    int h = gid & 3;
    const unsigned short* w = Wh + (size_t)(gid >> 2) * 256 + h * 64;
    const float* ai = sa + h * 144;
    const float* aj = ai + 64;
    float s0 = 0.f, s1 = 0.f;
#pragma unroll
    for (int d = 0; d < 64; d += 8) {
        bf16x8 wv = *(const bf16x8*)(w + d);
#pragma unroll
        for (int j = 0; j < 8; ++j) {
            float f = bf2f((unsigned short)wv[j]);
            s0 += f * ai[d + j];
            s1 += f * aj[d + j];
        }
    }
    si[gid] = s0;
    sj[gid] = s1;
}

// ---------------- per-edge attention (CSR order, coalesced eap) ----------------
__global__ void att_kernel(const int* __restrict__ srcp, const int* __restrict__ dstp,
                           const float* __restrict__ eap, const float* __restrict__ a,
                           const float* __restrict__ si, const float* __restrict__ sj,
                           float* __restrict__ attp) {
    __shared__ float ae[HEADS][EDGE_F];
    int tid = threadIdx.x;
    if (tid < HEADS * EDGE_F) ae[tid >> 4][tid & 15] = a[(tid >> 4) * 144 + 128 + (tid & 15)];
    __syncthreads();
    int i = blockIdx.x * blockDim.x + tid;
    if (i >= N_EDGES) return;
    int s = srcp[i], u = dstp[i];
    float4 siv = ((const float4*)si)[s];
    float4 sjv = ((const float4*)sj)[u];
    float x[16];
#pragma unroll
    for (int k = 0; k < 16; k += 4) {
        float4 v = *(const float4*)(eap + (size_t)i * 16 + k);
        x[k] = v.x; x[k + 1] = v.y; x[k + 2] = v.z; x[k + 3] = v.w;
    }
    float se0 = 0.f, se1 = 0.f, se2 = 0.f, se3 = 0.f;
#pragma unroll
    for (int k = 0; k < 16; ++k) {
        se0 += x[k] * ae[0][k];
        se1 += x[k] * ae[1][k];
        se2 += x[k] * ae[2][k];
        se3 += x[k] * ae[3][k];
    }
    float t0 = siv.x + sjv.x + se0;
    float t1 = siv.y + sjv.y + se1;
    float t2 = siv.z + sjv.z + se2;
    float t3 = siv.w + sjv.w + se3;
    t0 = t0 > 0.f ? t0 : LRELU_ALPHA * t0;
    t1 = t1 > 0.f ? t1 : LRELU_ALPHA * t1;
    t2 = t2 > 0.f ? t2 : LRELU_ALPHA * t2;
    t3 = t3 > 0.f ? t3 : LRELU_ALPHA * t3;
    float m = fmaxf(fmaxf(t0, t1), fmaxf(t2, t3));
    float p0 = __expf(t0 - m), p1 = __expf(t1 - m), p2 = __expf(t2 - m), p3 = __expf(t3 - m);
    float inv = 1.0f / (p0 + p1 + p2 + p3);
    ((float4*)attp)[i] = make_float4(p0 * inv, p1 * inv, p2 * inv, p3 * inv);
}

// ---------------- edge aggregation, 4 heads, concat + ELU ----------------
// one wave per node, 2 edges in flight: half-wave (32 lanes x ushort8) covers one 512B row
__global__ __launch_bounds__(256) void edge_agg_concat(
    const unsigned short* __restrict__ Whb, const float* __restrict__ attp,
    const int* __restrict__ row_ptr, const int* __restrict__ dstp,
    unsigned short* __restrict__ out) {
    int v = blockIdx.x * 4 + (threadIdx.x >> 6);
    if (v >= N_NODES) return;
    int l = threadIdx.x & 63;
    int half = l >> 5, p = l & 31;
    int h = p >> 3;
    int beg = row_ptr[v], end = row_ptr[v + 1];
    float acc[8] = {};
    int i = beg + half;
    int u_n = 0; float at_n = 0.f;
    if (i < end) { u_n = dstp[i]; at_n = attp[(size_t)i * 4 + h]; }
    for (; i < end; i += 2) {
        int u = u_n;
        float at = at_n;
        if (i + 2 < end) { u_n = dstp[i + 2]; at_n = attp[(size_t)(i + 2) * 4 + h]; }
        u16x8 wv = *(const u16x8*)(Whb + (size_t)u * 256 + p * 8);
#pragma unroll
        for (int j = 0; j < 8; ++j) acc[j] += at * bf2f(wv[j]);
    }
#pragma unroll
    for (int j = 0; j < 8; ++j) acc[j] += __shfl_xor(acc[j], 32, 64);
    if (half == 0) {
        u16x8 o;
#pragma unroll
        for (int j = 0; j < 8; ++j) o[j] = f2bf(eluf(acc[j]));
        *(u16x8*)(out + (size_t)v * 256 + p * 8) = o;
    }
}

// ---------------- edge aggregation, single head: 4 edges in flight ----------------
__global__ __launch_bounds__(256) void edge_agg_single(
    const unsigned short* __restrict__ Whb, const int* __restrict__ row_ptr,
    const int* __restrict__ dstp, float* __restrict__ out) {
    int v = blockIdx.x * 4 + (threadIdx.x >> 6);
    if (v >= N_NODES) return;
    int l = threadIdx.x & 63;
    int q = l >> 4, p = l & 15;
    int beg = row_ptr[v], end = row_ptr[v + 1];
    float acc[4] = {};
    for (int i = beg + q; i < end; i += 4) {
        int u = dstp[i];
        ushort4 w = *(const ushort4*)(Whb + (size_t)u * 64 + p * 4);
        acc[0] += bf2f(w.x); acc[1] += bf2f(w.y); acc[2] += bf2f(w.z); acc[3] += bf2f(w.w);
    }
#pragma unroll
    for (int j = 0; j < 4; ++j) {
        acc[j] += __shfl_xor(acc[j], 16, 64);
        acc[j] += __shfl_xor(acc[j], 32, 64);
    }
    if (l < 16) {
        float4 o = make_float4(acc[0], acc[1], acc[2], acc[3]);
        *(float4*)(out + (size_t)v * 64 + p * 4) = o;
    }
}

// ---------------- mean pool per graph (batch sorted), 16 waves per graph ----------------
__global__ __launch_bounds__(1024) void pool_kernel(const float* __restrict__ h3,
                                                    const int* __restrict__ batch,
                                                    float* __restrict__ pooled) {
    int g = blockIdx.x;
    int lane = threadIdx.x & 63;
    int wave = threadIdx.x >> 6;
    int lo = 0, hi = N_NODES;
    while (lo < hi) { int mid = (lo + hi) >> 1; if (batch[mid] < g) lo = mid + 1; else hi = mid; }
    int start = lo;
    lo = start; hi = N_NODES;
    while (lo < hi) { int mid = (lo + hi) >> 1; if (batch[mid] < g + 1) lo = mid + 1; else hi = mid; }
    int endi = lo;
    float s = 0.f;
    for (int v = start + wave; v < endi; v += 16) s += h3[(size_t)v * 64 + lane];
    __shared__ float red[16][64];
    red[wave][lane] = s;
    __syncthreads();
    if (wave == 0) {
        float t = red[0][lane];
#pragma unroll
        for (int w = 1; w < 16; ++w) t += red[w][lane];
        float c = (float)((endi - start) > 1 ? (endi - start) : 1);
        pooled[g * 64 + lane] = t / c;
    }
}

// ---------------- classifier + log_softmax ----------------
__global__ void classify_kernel(const float* __restrict__ pooled, const float* __restrict__ cw,
                                const float* __restrict__ cb, float* __restrict__ out) {
    int g = threadIdx.x;
    if (g >= NUM_GRAPHS) return;
    float lg[NUM_CLASSES];
#pragma unroll
    for (int c = 0; c < NUM_CLASSES; ++c) lg[c] = cb[c];
    for (int d = 0; d < OUT_F; ++d) {
        float p = pooled[g * 64 + d];
#pragma unroll
        for (int c = 0; c < NUM_CLASSES; ++c) lg[c] += p * cw[d * NUM_CLASSES + c];
    }
    float m = lg[0];
#pragma unroll
    for (int c = 1; c < NUM_CLASSES; ++c) m = fmaxf(m, lg[c]);
    float s = 0.f;
#pragma unroll
    for (int c = 0; c < NUM_CLASSES; ++c) s += expf(lg[c] - m);
    float lse = m + logf(s);
#pragma unroll
    for (int c = 0; c < NUM_CLASSES; ++c) out[g * NUM_CLASSES + c] = lg[c] - lse;
}

extern "C" void kernel_launch(void* const* d_in, const int* in_sizes, int n_in,
                              void* d_out, int out_size, void* d_ws, size_t ws_size,
                              hipStream_t stream) {
    const float* x   = (const float*)d_in[0];
    const int*   ei  = (const int*)d_in[1];
    const float* ea  = (const float*)d_in[2];
    const int* batch = (const int*)d_in[3];
    const float* W0  = (const float*)d_in[4];
    const float* a0  = (const float*)d_in[5];
    const float* W1  = (const float*)d_in[6];
    const float* a1  = (const float*)d_in[7];
    const float* W2  = (const float*)d_in[8];
    const float* cw  = (const float*)d_in[10];
    const float* cb  = (const float*)d_in[11];
    float* out = (float*)d_out;

    const int* srcg = ei;
    const int* dstg = ei + N_EDGES;

    char* ws = (char*)d_ws;
    size_t off = 0;
    auto alloc = [&](size_t bytes) -> char* {
        char* p = ws + off;
        off += (bytes + 255) & ~(size_t)255;
        return p;
    };
    unsigned short* W0b  = (unsigned short*)alloc(256 * 256 * 2);
    unsigned short* W1b  = (unsigned short*)alloc(256 * 256 * 2);
    unsigned short* W2b  = (unsigned short*)alloc(256 * 64 * 2);
    unsigned short* Whb  = (unsigned short*)alloc((size_t)N_NODES * 256 * 2);
    unsigned short* hAb  = (unsigned short*)alloc((size_t)N_NODES * 256 * 2);
    unsigned short* hBb  = (unsigned short*)alloc((size_t)N_NODES * 256 * 2);
    unsigned short* Wh2b = (unsigned short*)alloc((size_t)N_NODES * 64 * 2);
    float* si   = (float*)alloc((size_t)N_NODES * HEADS * 4);
    float* sj   = (float*)alloc((size_t)N_NODES * HEADS * 4);
    float* attp = (float*)alloc((size_t)N_EDGES * HEADS * 4);
    float* eap  = (float*)alloc((size_t)N_EDGES * EDGE_F * 4);
    int* row_ptr = (int*)alloc((N_NODES + 1) * 4);
    int* cnt  = (int*)alloc(N_NODES * 4);
    int* srcp = (int*)alloc(N_EDGES * 4);
    int* dstp = (int*)alloc(N_EDGES * 4);
    float* h3 = (float*)alloc((size_t)N_NODES * 64 * 4);
    float* pooled = (float*)alloc(NUM_GRAPHS * 64 * 4);

    // weight converts (x handled in-GEMM)
    f2bf_kernel<<<(256 * 256 / 4 + 255) / 256, 256, 0, stream>>>(W0, W0b, 256 * 256 / 4);
    f2bf_kernel<<<(256 * 256 / 4 + 255) / 256, 256, 0, stream>>>(W1, W1b, 256 * 256 / 4);
    f2bf_kernel<<<(256 * 64 / 4 + 255) / 256, 256, 0, stream>>>(W2, W2b, 256 * 64 / 4);

    // CSR build (shared by all three layers); also permutes edge_attr into CSR order
    hipMemsetAsync(cnt, 0, N_NODES * 4, stream);
    count_kernel<<<(N_EDGES + 255) / 256, 256, 0, stream>>>(srcg, cnt);
    scan_kernel<<<1, 1024, 0, stream>>>(cnt, row_ptr);
    hipMemsetAsync(cnt, 0, N_NODES * 4, stream);
    scatter_kernel<<<(N_EDGES + 255) / 256, 256, 0, stream>>>(srcg, dstg, ea, row_ptr, cnt,
                                                              srcp, dstp, eap);

    dim3 ggrid((N_NODES + 63) / 64, 4);
    dim3 ggrid2((N_NODES + 63) / 64, 1);
    int nsb = (N_NODES * HEADS + 255) / 256;
    int atb = (N_EDGES + 255) / 256;
    int agb = (N_NODES + 3) / 4;

    // layer 0 (A = x, fp32)
    gemm_bf16<true><<<ggrid, 256, 0, stream>>>(x, W0b, Whb, N_NODES, 256, 256);
    node_scores<<<nsb, 256, 0, stream>>>(Whb, a0, si, sj);
    att_kernel<<<atb, 256, 0, stream>>>(srcp, dstp, eap, a0, si, sj, attp);
    edge_agg_concat<<<agb, 256, 0, stream>>>(Whb, attp, row_ptr, dstp, hAb);

    // layer 1
    gemm_bf16<false><<<ggrid, 256, 0, stream>>>(hAb, W1b, Whb, N_NODES, 256, 256);
    node_scores<<<nsb, 256, 0, stream>>>(Whb, a1, si, sj);
    att_kernel<<<atb, 256, 0, stream>>>(srcp, dstp, eap, a1, si, sj, attp);
    edge_agg_concat<<<agb, 256, 0, stream>>>(Whb, attp, row_ptr, dstp, hBb);

    // layer 2 (single head, att == 1, mean over 1 head = identity)
    gemm_bf16<false><<<ggrid2, 256, 0, stream>>>(hBb, W2b, Wh2b, N_NODES, 64, 256);
    edge_agg_single<<<agb, 256, 0, stream>>>(Wh2b, row_ptr, dstp, h3);

    // pooling + classifier
    pool_kernel<<<NUM_GRAPHS, 1024, 0, stream>>>(h3, batch, pooled);
    classify_kernel<<<1, 64, 0, stream>>>(pooled, cw, cb, out);
}

// Round 5
// 209.255 us; speedup vs baseline: 2.5986x; 1.0789x over previous
//
#include <hip/hip_runtime.h>
#include <hip/hip_bf16.h>
#include <math.h>

#define N_NODES 20000
#define N_EDGES 320000
#define IN_F 256
#define HID 64
#define HEADS 4
#define OUT_F 64
#define EDGE_F 16
#define NUM_CLASSES 10
#define NUM_GRAPHS 40
#define LRELU_ALPHA 0.2f

typedef short bf16x8 __attribute__((ext_vector_type(8)));
typedef unsigned short u16x8 __attribute__((ext_vector_type(8)));
typedef float f32x4 __attribute__((ext_vector_type(4)));

static __device__ __forceinline__ float bf2f(unsigned short u) {
    union { unsigned int i; float f; } v; v.i = ((unsigned int)u) << 16; return v.f;
}
static __device__ __forceinline__ unsigned short f2bf(float f) {
    union { float f; unsigned int i; } v; v.f = f;
    unsigned int r = v.i + 0x7FFF + ((v.i >> 16) & 1);
    return (unsigned short)(r >> 16);
}
static __device__ __forceinline__ float eluf(float a) {
    return a > 0.f ? a : __expf(a) - 1.0f;
}

// ---------------- fused weight converts: W0|W1|W2 -> bf16 in one dispatch ----------------
__global__ void wconv_kernel(const float* __restrict__ W0, const float* __restrict__ W1,
                             const float* __restrict__ W2, unsigned short* __restrict__ W0b,
                             unsigned short* __restrict__ W1b, unsigned short* __restrict__ W2b) {
    int i = blockIdx.x * blockDim.x + threadIdx.x;  // float4 units
    const float* src; unsigned short* dst; int off;
    if (i < 16384)      { src = W0; dst = W0b; off = i; }
    else if (i < 32768) { src = W1; dst = W1b; off = i - 16384; }
    else if (i < 36864) { src = W2; dst = W2b; off = i - 32768; }
    else return;
    float4 v = ((const float4*)src)[off];
    ushort4 o;
    o.x = f2bf(v.x); o.y = f2bf(v.y); o.z = f2bf(v.z); o.w = f2bf(v.w);
    ((ushort4*)dst)[off] = o;
}

// ---------------- CSR build ----------------
__global__ void count_kernel(const int* __restrict__ src, int* __restrict__ cnt) {
    int e = blockIdx.x * blockDim.x + threadIdx.x;
    if (e < N_EDGES) atomicAdd(&cnt[src[e]], 1);
}

// scan: row_ptr (inclusive shifted) + cursor = exclusive prefix (row start offsets)
__global__ __launch_bounds__(1024) void scan_kernel(const int* __restrict__ cnt,
                                                    int* __restrict__ row_ptr,
                                                    int* __restrict__ cursor) {
    __shared__ int wsum[16];
    __shared__ int carry_s;
    int t = threadIdx.x;
    int lane = t & 63, wave = t >> 6;
    if (t == 0) { carry_s = 0; row_ptr[0] = 0; }
    __syncthreads();
    for (int base = 0; base < N_NODES; base += 1024) {
        int idx = base + t;
        int x0 = (idx < N_NODES) ? cnt[idx] : 0;
        int x = x0;
#pragma unroll
        for (int off = 1; off < 64; off <<= 1) {
            int y = __shfl_up(x, off, 64);
            if (lane >= off) x += y;
        }
        if (lane == 63) wsum[wave] = x;
        __syncthreads();
        if (wave == 0 && lane < 16) {
            int s = wsum[lane];
#pragma unroll
            for (int off = 1; off < 16; off <<= 1) {
                int y = __shfl_up(s, off, 64);
                if (lane >= off) s += y;
            }
            wsum[lane] = s;
        }
        __syncthreads();
        int waveoff = (wave > 0) ? wsum[wave - 1] : 0;
        int carry = carry_s;
        if (idx < N_NODES) {
            int incl = x + waveoff + carry;
            row_ptr[idx + 1] = incl;
            cursor[idx] = incl - x0;   // row start
        }
        __syncthreads();
        if (t == 0) carry_s = carry + wsum[15];
        __syncthreads();
    }
}

// scatter: build CSR-ordered src/dst AND permute edge_attr rows into CSR order
__global__ void scatter_kernel(const int* __restrict__ src, const int* __restrict__ dst,
                               const float* __restrict__ ea, int* __restrict__ cursor,
                               int* __restrict__ srcp, int* __restrict__ dstp,
                               float* __restrict__ eap) {
    int e = blockIdx.x * blockDim.x + threadIdx.x;
    if (e < N_EDGES) {
        int s = src[e];
        int pos = atomicAdd(&cursor[s], 1);
        srcp[pos] = s;
        dstp[pos] = dst[e];
#pragma unroll
        for (int k = 0; k < 4; ++k)
            ((float4*)(eap + (size_t)pos * 16))[k] = ((const float4*)(ea + (size_t)e * 16))[k];
    }
}

// ---------------- bf16 MFMA GEMM + optional fused attention scores ----------------
// A fp32 or bf16, B/C bf16, fp32 accumulate. K%32==0, N%64==0, M guarded.
// SCORES: N-block == head; compute si/sj for this head from the C tile.
template <bool AF32, bool SCORES>
__global__ __launch_bounds__(256) void gemm_bf16(const void* __restrict__ Aptr,
                                                 const unsigned short* __restrict__ B,
                                                 unsigned short* __restrict__ C,
                                                 const float* __restrict__ avec,
                                                 float* __restrict__ si, float* __restrict__ sj,
                                                 int M, int N, int K) {
    __shared__ unsigned short As[64][40];
    __shared__ unsigned short Bs[64][40];   // [n][k] (transposed)
    __shared__ unsigned short Cs[64][72];
    __shared__ float sa[128];
    int tid = threadIdx.x;
    if (SCORES && tid < 128) sa[tid] = avec[blockIdx.y * 144 + tid];
    int bm = blockIdx.x * 64, bn = blockIdx.y * 64;
    int w = tid >> 6, l = tid & 63;
    int wr = (w >> 1) * 32, wc = (w & 1) * 32;
    int lr = l & 15, lk = (l >> 4) * 8;
    f32x4 acc[2][2] = {};
    int ar = tid >> 2, akc = (tid & 3) * 8;
    int bk = tid >> 3, bn8 = tid & 7, bnc = bn8 * 8;

    for (int k0 = 0; k0 < K; k0 += 32) {
        bf16x8 av = {};
        if (bm + ar < M) {
            if constexpr (AF32) {
                const float* Af = (const float*)Aptr + (size_t)(bm + ar) * K + k0 + akc;
                float4 f0 = *(const float4*)Af;
                float4 f1 = *(const float4*)(Af + 4);
                av[0] = (short)f2bf(f0.x); av[1] = (short)f2bf(f0.y);
                av[2] = (short)f2bf(f0.z); av[3] = (short)f2bf(f0.w);
                av[4] = (short)f2bf(f1.x); av[5] = (short)f2bf(f1.y);
                av[6] = (short)f2bf(f1.z); av[7] = (short)f2bf(f1.w);
            } else {
                av = *(const bf16x8*)((const unsigned short*)Aptr + (size_t)(bm + ar) * K + k0 + akc);
            }
        }
        *(bf16x8*)&As[ar][akc] = av;
        bf16x8 bv = *(const bf16x8*)(B + (size_t)(k0 + bk) * N + bn + bnc);
#pragma unroll
        for (int j = 0; j < 8; ++j) {
            int jj = (j + bn8) & 7;  // rotate write order to spread banks
            Bs[bnc + jj][bk] = (unsigned short)bv[jj];
        }
        __syncthreads();
        bf16x8 a0 = *(const bf16x8*)&As[wr + lr][lk];
        bf16x8 a1 = *(const bf16x8*)&As[wr + 16 + lr][lk];
        bf16x8 b0 = *(const bf16x8*)&Bs[wc + lr][lk];
        bf16x8 b1 = *(const bf16x8*)&Bs[wc + 16 + lr][lk];
        acc[0][0] = __builtin_amdgcn_mfma_f32_16x16x32_bf16(a0, b0, acc[0][0], 0, 0, 0);
        acc[0][1] = __builtin_amdgcn_mfma_f32_16x16x32_bf16(a0, b1, acc[0][1], 0, 0, 0);
        acc[1][0] = __builtin_amdgcn_mfma_f32_16x16x32_bf16(a1, b0, acc[1][0], 0, 0, 0);
        acc[1][1] = __builtin_amdgcn_mfma_f32_16x16x32_bf16(a1, b1, acc[1][1], 0, 0, 0);
        __syncthreads();
    }
    // D layout: col = lane&15, row = (lane>>4)*4 + reg
#pragma unroll
    for (int i = 0; i < 2; ++i)
#pragma unroll
        for (int j = 0; j < 2; ++j)
#pragma unroll
            for (int r = 0; r < 4; ++r)
                Cs[wr + i * 16 + (l >> 4) * 4 + r][wc + j * 16 + (l & 15)] = f2bf(acc[i][j][r]);
    __syncthreads();
    int row = tid >> 3, cc = (tid & 7) * 8;
#pragma unroll
    for (int p = 0; p < 2; ++p, row += 32) {
        if (bm + row < M) {
            bf16x8 o = *(const bf16x8*)&Cs[row][cc];
            *(bf16x8*)(C + (size_t)(bm + row) * N + bn + cc) = o;
        }
    }
    if (SCORES) {
        int r = tid >> 2, qq = tid & 3;
        float s0 = 0.f, s1 = 0.f;
#pragma unroll
        for (int k = 0; k < 16; ++k) {
            float f = bf2f(Cs[r][qq * 16 + k]);
            s0 += f * sa[qq * 16 + k];
            s1 += f * sa[64 + qq * 16 + k];
        }
        s0 += __shfl_xor(s0, 1, 64); s0 += __shfl_xor(s0, 2, 64);
        s1 += __shfl_xor(s1, 1, 64); s1 += __shfl_xor(s1, 2, 64);
        if (qq == 0 && bm + r < M) {
            si[(size_t)(bm + r) * 4 + blockIdx.y] = s0;
            sj[(size_t)(bm + r) * 4 + blockIdx.y] = s1;
        }
    }
}

// ---------------- per-edge attention (CSR order, coalesced eap) ----------------
__global__ void att_kernel(const int* __restrict__ srcp, const int* __restrict__ dstp,
                           const float* __restrict__ eap, const float* __restrict__ a,
                           const float* __restrict__ si, const float* __restrict__ sj,
                           float* __restrict__ attp) {
    __shared__ float ae[HEADS][EDGE_F];
    int tid = threadIdx.x;
    if (tid < HEADS * EDGE_F) ae[tid >> 4][tid & 15] = a[(tid >> 4) * 144 + 128 + (tid & 15)];
    __syncthreads();
    int i = blockIdx.x * blockDim.x + tid;
    if (i >= N_EDGES) return;
    int s = srcp[i], u = dstp[i];
    float4 siv = ((const float4*)si)[s];
    float4 sjv = ((const float4*)sj)[u];
    float x[16];
#pragma unroll
    for (int k = 0; k < 16; k += 4) {
        float4 v = *(const float4*)(eap + (size_t)i * 16 + k);
        x[k] = v.x; x[k + 1] = v.y; x[k + 2] = v.z; x[k + 3] = v.w;
    }
    float se0 = 0.f, se1 = 0.f, se2 = 0.f, se3 = 0.f;
#pragma unroll
    for (int k = 0; k < 16; ++k) {
        se0 += x[k] * ae[0][k];
        se1 += x[k] * ae[1][k];
        se2 += x[k] * ae[2][k];
        se3 += x[k] * ae[3][k];
    }
    float t0 = siv.x + sjv.x + se0;
    float t1 = siv.y + sjv.y + se1;
    float t2 = siv.z + sjv.z + se2;
    float t3 = siv.w + sjv.w + se3;
    t0 = t0 > 0.f ? t0 : LRELU_ALPHA * t0;
    t1 = t1 > 0.f ? t1 : LRELU_ALPHA * t1;
    t2 = t2 > 0.f ? t2 : LRELU_ALPHA * t2;
    t3 = t3 > 0.f ? t3 : LRELU_ALPHA * t3;
    float m = fmaxf(fmaxf(t0, t1), fmaxf(t2, t3));
    float p0 = __expf(t0 - m), p1 = __expf(t1 - m), p2 = __expf(t2 - m), p3 = __expf(t3 - m);
    float inv = 1.0f / (p0 + p1 + p2 + p3);
    ((float4*)attp)[i] = make_float4(p0 * inv, p1 * inv, p2 * inv, p3 * inv);
}

// ---------------- edge aggregation, 4 heads, concat + ELU ----------------
// one wave per node, 4 edge-slots x 16 lanes; each lane covers two 16B row-halves
// -> 8 independent 128B gathers in flight per wave
__global__ __launch_bounds__(256) void edge_agg_concat(
    const unsigned short* __restrict__ Whb, const float* __restrict__ attp,
    const int* __restrict__ row_ptr, const int* __restrict__ dstp,
    unsigned short* __restrict__ out) {
    int v = blockIdx.x * 4 + (threadIdx.x >> 6);
    if (v >= N_NODES) return;
    int l = threadIdx.x & 63;
    int slot = l >> 4, p = l & 15;
    int beg = row_ptr[v], end = row_ptr[v + 1];
    float acc0[8] = {}, acc1[8] = {};
    int i = beg + slot;
    int u_n = 0;
    float4 at_n = make_float4(0.f, 0.f, 0.f, 0.f);
    if (i < end) { u_n = dstp[i]; at_n = ((const float4*)attp)[i]; }
    for (; i < end; i += 4) {
        int u = u_n;
        float4 at4 = at_n;
        if (i + 4 < end) { u_n = dstp[i + 4]; at_n = ((const float4*)attp)[i + 4]; }
        const unsigned short* row = Whb + (size_t)u * 256;
        u16x8 w0 = *(const u16x8*)(row + p * 8);         // dims p*8..+8   (heads 0/1)
        u16x8 w1 = *(const u16x8*)(row + 128 + p * 8);   // dims 128+p*8.. (heads 2/3)
        float atA = (p & 8) ? at4.y : at4.x;
        float atB = (p & 8) ? at4.w : at4.z;
#pragma unroll
        for (int j = 0; j < 8; ++j) acc0[j] += atA * bf2f(w0[j]);
#pragma unroll
        for (int j = 0; j < 8; ++j) acc1[j] += atB * bf2f(w1[j]);
    }
#pragma unroll
    for (int j = 0; j < 8; ++j) {
        acc0[j] += __shfl_xor(acc0[j], 16, 64);
        acc0[j] += __shfl_xor(acc0[j], 32, 64);
        acc1[j] += __shfl_xor(acc1[j], 16, 64);
        acc1[j] += __shfl_xor(acc1[j], 32, 64);
    }
    if (slot == 0) {
        u16x8 o0, o1;
#pragma unroll
        for (int j = 0; j < 8; ++j) {
            o0[j] = f2bf(eluf(acc0[j]));
            o1[j] = f2bf(eluf(acc1[j]));
        }
        *(u16x8*)(out + (size_t)v * 256 + p * 8) = o0;
        *(u16x8*)(out + (size_t)v * 256 + 128 + p * 8) = o1;
    }
}

// ---------------- edge aggregation, single head: 8 edges in flight ----------------
__global__ __launch_bounds__(256) void edge_agg_single(
    const unsigned short* __restrict__ Whb, const int* __restrict__ row_ptr,
    const int* __restrict__ dstp, float* __restrict__ out) {
    int v = blockIdx.x * 4 + (threadIdx.x >> 6);
    if (v >= N_NODES) return;
    int l = threadIdx.x & 63;
    int slot = l >> 3, p = l & 7;
    int beg = row_ptr[v], end = row_ptr[v + 1];
    float acc[8] = {};
    int i = beg + slot;
    int u_n = 0;
    if (i < end) u_n = dstp[i];
    for (; i < end; i += 8) {
        int u = u_n;
        if (i + 8 < end) u_n = dstp[i + 8];
        u16x8 w = *(const u16x8*)(Whb + (size_t)u * 64 + p * 8);
#pragma unroll
        for (int j = 0; j < 8; ++j) acc[j] += bf2f(w[j]);
    }
#pragma unroll
    for (int j = 0; j < 8; ++j) {
        acc[j] += __shfl_xor(acc[j], 8, 64);
        acc[j] += __shfl_xor(acc[j], 16, 64);
        acc[j] += __shfl_xor(acc[j], 32, 64);
    }
    if (l < 8) {
        float4 o0 = make_float4(acc[0], acc[1], acc[2], acc[3]);
        float4 o1 = make_float4(acc[4], acc[5], acc[6], acc[7]);
        *(float4*)(out + (size_t)v * 64 + p * 8) = o0;
        *(float4*)(out + (size_t)v * 64 + p * 8 + 4) = o1;
    }
}

// ---------------- mean pool per graph (batch sorted), 16 waves per graph ----------------
__global__ __launch_bounds__(1024) void pool_kernel(const float* __restrict__ h3,
                                                    const int* __restrict__ batch,
                                                    float* __restrict__ pooled) {
    int g = blockIdx.x;
    int lane = threadIdx.x & 63;
    int wave = threadIdx.x >> 6;
    int lo = 0, hi = N_NODES;
    while (lo < hi) { int mid = (lo + hi) >> 1; if (batch[mid] < g) lo = mid + 1; else hi = mid; }
    int start = lo;
    lo = start; hi = N_NODES;
    while (lo < hi) { int mid = (lo + hi) >> 1; if (batch[mid] < g + 1) lo = mid + 1; else hi = mid; }
    int endi = lo;
    float s = 0.f;
    for (int v = start + wave; v < endi; v += 16) s += h3[(size_t)v * 64 + lane];
    __shared__ float red[16][64];
    red[wave][lane] = s;
    __syncthreads();
    if (wave == 0) {
        float t = red[0][lane];
#pragma unroll
        for (int w = 1; w < 16; ++w) t += red[w][lane];
        float c = (float)((endi - start) > 1 ? (endi - start) : 1);
        pooled[g * 64 + lane] = t / c;
    }
}

// ---------------- classifier + log_softmax ----------------
__global__ void classify_kernel(const float* __restrict__ pooled, const float* __restrict__ cw,
                                const float* __restrict__ cb, float* __restrict__ out) {
    int g = threadIdx.x;
    if (g >= NUM_GRAPHS) return;
    float lg[NUM_CLASSES];
#pragma unroll
    for (int c = 0; c < NUM_CLASSES; ++c) lg[c] = cb[c];
    for (int d = 0; d < OUT_F; ++d) {
        float p = pooled[g * 64 + d];
#pragma unroll
        for (int c = 0; c < NUM_CLASSES; ++c) lg[c] += p * cw[d * NUM_CLASSES + c];
    }
    float m = lg[0];
#pragma unroll
    for (int c = 1; c < NUM_CLASSES; ++c) m = fmaxf(m, lg[c]);
    float s = 0.f;
#pragma unroll
    for (int c = 0; c < NUM_CLASSES; ++c) s += expf(lg[c] - m);
    float lse = m + logf(s);
#pragma unroll
    for (int c = 0; c < NUM_CLASSES; ++c) out[g * NUM_CLASSES + c] = lg[c] - lse;
}

extern "C" void kernel_launch(void* const* d_in, const int* in_sizes, int n_in,
                              void* d_out, int out_size, void* d_ws, size_t ws_size,
                              hipStream_t stream) {
    const float* x   = (const float*)d_in[0];
    const int*   ei  = (const int*)d_in[1];
    const float* ea  = (const float*)d_in[2];
    const int* batch = (const int*)d_in[3];
    const float* W0  = (const float*)d_in[4];
    const float* a0  = (const float*)d_in[5];
    const float* W1  = (const float*)d_in[6];
    const float* a1  = (const float*)d_in[7];
    const float* W2  = (const float*)d_in[8];
    const float* cw  = (const float*)d_in[10];
    const float* cb  = (const float*)d_in[11];
    float* out = (float*)d_out;

    const int* srcg = ei;
    const int* dstg = ei + N_EDGES;

    char* ws = (char*)d_ws;
    size_t off = 0;
    auto alloc = [&](size_t bytes) -> char* {
        char* p = ws + off;
        off += (bytes + 255) & ~(size_t)255;
        return p;
    };
    unsigned short* W0b  = (unsigned short*)alloc(256 * 256 * 2);
    unsigned short* W1b  = (unsigned short*)alloc(256 * 256 * 2);
    unsigned short* W2b  = (unsigned short*)alloc(256 * 64 * 2);
    unsigned short* Whb  = (unsigned short*)alloc((size_t)N_NODES * 256 * 2);
    unsigned short* hAb  = (unsigned short*)alloc((size_t)N_NODES * 256 * 2);
    unsigned short* hBb  = (unsigned short*)alloc((size_t)N_NODES * 256 * 2);
    unsigned short* Wh2b = (unsigned short*)alloc((size_t)N_NODES * 64 * 2);
    float* si   = (float*)alloc((size_t)N_NODES * HEADS * 4);
    float* sj   = (float*)alloc((size_t)N_NODES * HEADS * 4);
    float* attp = (float*)alloc((size_t)N_EDGES * HEADS * 4);
    float* eap  = (float*)alloc((size_t)N_EDGES * EDGE_F * 4);
    int* row_ptr = (int*)alloc((N_NODES + 1) * 4);
    int* cursor  = (int*)alloc(N_NODES * 4);
    int* cnt  = (int*)alloc(N_NODES * 4);
    int* srcp = (int*)alloc(N_EDGES * 4);
    int* dstp = (int*)alloc(N_EDGES * 4);
    float* h3 = (float*)alloc((size_t)N_NODES * 64 * 4);
    float* pooled = (float*)alloc(NUM_GRAPHS * 64 * 4);

    // weight converts (one dispatch); x converts in-GEMM
    wconv_kernel<<<144, 256, 0, stream>>>(W0, W1, W2, W0b, W1b, W2b);

    // CSR build (shared by all three layers); also permutes edge_attr into CSR order
    hipMemsetAsync(cnt, 0, N_NODES * 4, stream);
    count_kernel<<<(N_EDGES + 255) / 256, 256, 0, stream>>>(srcg, cnt);
    scan_kernel<<<1, 1024, 0, stream>>>(cnt, row_ptr, cursor);
    scatter_kernel<<<(N_EDGES + 255) / 256, 256, 0, stream>>>(srcg, dstg, ea, cursor,
                                                              srcp, dstp, eap);

    dim3 ggrid((N_NODES + 63) / 64, 4);
    dim3 ggrid2((N_NODES + 63) / 64, 1);
    int atb = (N_EDGES + 255) / 256;
    int agb = (N_NODES + 3) / 4;

    // layer 0 (A = x fp32, scores fused)
    gemm_bf16<true, true><<<ggrid, 256, 0, stream>>>(x, W0b, Whb, a0, si, sj, N_NODES, 256, 256);
    att_kernel<<<atb, 256, 0, stream>>>(srcp, dstp, eap, a0, si, sj, attp);
    edge_agg_concat<<<agb, 256, 0, stream>>>(Whb, attp, row_ptr, dstp, hAb);

    // layer 1
    gemm_bf16<false, true><<<ggrid, 256, 0, stream>>>(hAb, W1b, Whb, a1, si, sj, N_NODES, 256, 256);
    att_kernel<<<atb, 256, 0, stream>>>(srcp, dstp, eap, a1, si, sj, attp);
    edge_agg_concat<<<agb, 256, 0, stream>>>(Whb, attp, row_ptr, dstp, hBb);

    // layer 2 (single head, att == 1, mean over 1 head = identity)
    gemm_bf16<false, false><<<ggrid2, 256, 0, stream>>>(hBb, W2b, Wh2b, nullptr, nullptr, nullptr,
                                                        N_NODES, 64, 256);
    edge_agg_single<<<agb, 256, 0, stream>>>(Wh2b, row_ptr, dstp, h3);

    // pooling + classifier
    pool_kernel<<<NUM_GRAPHS, 1024, 0, stream>>>(h3, batch, pooled);
    classify_kernel<<<1, 64, 0, stream>>>(pooled, cw, cb, out);
}

// Round 6
// 207.772 us; speedup vs baseline: 2.6172x; 1.0071x over previous
//
#include <hip/hip_runtime.h>
#include <hip/hip_bf16.h>
#include <math.h>

#define N_NODES 20000
#define N_EDGES 320000
#define IN_F 256
#define HID 64
#define HEADS 4
#define OUT_F 64
#define EDGE_F 16
#define NUM_CLASSES 10
#define NUM_GRAPHS 40
#define LRELU_ALPHA 0.2f

typedef short bf16x8 __attribute__((ext_vector_type(8)));
typedef unsigned short u16x8 __attribute__((ext_vector_type(8)));
typedef float f32x4 __attribute__((ext_vector_type(4)));

static __device__ __forceinline__ float bf2f(unsigned short u) {
    union { unsigned int i; float f; } v; v.i = ((unsigned int)u) << 16; return v.f;
}
static __device__ __forceinline__ unsigned short f2bf(float f) {
    union { float f; unsigned int i; } v; v.f = f;
    unsigned int r = v.i + 0x7FFF + ((v.i >> 16) & 1);
    return (unsigned short)(r >> 16);
}
static __device__ __forceinline__ float eluf(float a) {
    return a > 0.f ? a : __expf(a) - 1.0f;
}

// ---------------- prep: weight converts (bf16) + zero cnt, one dispatch ----------------
__global__ void prep_kernel(const float* __restrict__ W0, const float* __restrict__ W1,
                            const float* __restrict__ W2, unsigned short* __restrict__ W0b,
                            unsigned short* __restrict__ W1b, unsigned short* __restrict__ W2b,
                            int* __restrict__ cnt) {
    int b = blockIdx.x;
    if (b < 144) {
        int i = b * 256 + threadIdx.x;  // float4 units
        const float* src; unsigned short* dst; int off;
        if (i < 16384)      { src = W0; dst = W0b; off = i; }
        else if (i < 32768) { src = W1; dst = W1b; off = i - 16384; }
        else                { src = W2; dst = W2b; off = i - 32768; }
        float4 v = ((const float4*)src)[off];
        ushort4 o;
        o.x = f2bf(v.x); o.y = f2bf(v.y); o.z = f2bf(v.z); o.w = f2bf(v.w);
        ((ushort4*)dst)[off] = o;
    } else {
        int j = (b - 144) * 256 + threadIdx.x;  // int4 units
        if (j < N_NODES / 4) ((int4*)cnt)[j] = make_int4(0, 0, 0, 0);
    }
}

// ---------------- CSR build ----------------
__global__ void count_kernel(const int* __restrict__ src, int* __restrict__ cnt) {
    int e = blockIdx.x * blockDim.x + threadIdx.x;
    if (e < N_EDGES) atomicAdd(&cnt[src[e]], 1);
}

// scan: row_ptr (inclusive shifted) + cursor = exclusive prefix (row start offsets)
__global__ __launch_bounds__(1024) void scan_kernel(const int* __restrict__ cnt,
                                                    int* __restrict__ row_ptr,
                                                    int* __restrict__ cursor) {
    __shared__ int wsum[16];
    __shared__ int carry_s;
    int t = threadIdx.x;
    int lane = t & 63, wave = t >> 6;
    if (t == 0) { carry_s = 0; row_ptr[0] = 0; }
    __syncthreads();
    for (int base = 0; base < N_NODES; base += 1024) {
        int idx = base + t;
        int x0 = (idx < N_NODES) ? cnt[idx] : 0;
        int x = x0;
#pragma unroll
        for (int off = 1; off < 64; off <<= 1) {
            int y = __shfl_up(x, off, 64);
            if (lane >= off) x += y;
        }
        if (lane == 63) wsum[wave] = x;
        __syncthreads();
        if (wave == 0 && lane < 16) {
            int s = wsum[lane];
#pragma unroll
            for (int off = 1; off < 16; off <<= 1) {
                int y = __shfl_up(s, off, 64);
                if (lane >= off) s += y;
            }
            wsum[lane] = s;
        }
        __syncthreads();
        int waveoff = (wave > 0) ? wsum[wave - 1] : 0;
        int carry = carry_s;
        if (idx < N_NODES) {
            int incl = x + waveoff + carry;
            row_ptr[idx + 1] = incl;
            cursor[idx] = incl - x0;   // row start
        }
        __syncthreads();
        if (t == 0) carry_s = carry + wsum[15];
        __syncthreads();
    }
}

// scatter: CSR-ordered dst + per-edge edge-feature scores for BOTH concat layers
__global__ void scatter_kernel(const int* __restrict__ src, const int* __restrict__ dst,
                               const float* __restrict__ ea, const float* __restrict__ a0,
                               const float* __restrict__ a1, int* __restrict__ cursor,
                               int* __restrict__ dstp, float* __restrict__ se0,
                               float* __restrict__ se1) {
    __shared__ float ae[2][4][16];
    int tid = threadIdx.x;
    if (tid < 64) ae[0][tid >> 4][tid & 15] = a0[(tid >> 4) * 144 + 128 + (tid & 15)];
    else if (tid < 128) { int t = tid - 64; ae[1][t >> 4][t & 15] = a1[(t >> 4) * 144 + 128 + (t & 15)]; }
    __syncthreads();
    int e = blockIdx.x * blockDim.x + tid;
    if (e >= N_EDGES) return;
    int s = src[e];
    int pos = atomicAdd(&cursor[s], 1);
    dstp[pos] = dst[e];
    float x[16];
#pragma unroll
    for (int k = 0; k < 16; k += 4) {
        float4 v = *(const float4*)(ea + (size_t)e * 16 + k);
        x[k] = v.x; x[k + 1] = v.y; x[k + 2] = v.z; x[k + 3] = v.w;
    }
    float4 o0 = make_float4(0.f, 0.f, 0.f, 0.f), o1 = o0;
#pragma unroll
    for (int k = 0; k < 16; ++k) {
        o0.x += x[k] * ae[0][0][k]; o0.y += x[k] * ae[0][1][k];
        o0.z += x[k] * ae[0][2][k]; o0.w += x[k] * ae[0][3][k];
        o1.x += x[k] * ae[1][0][k]; o1.y += x[k] * ae[1][1][k];
        o1.z += x[k] * ae[1][2][k]; o1.w += x[k] * ae[1][3][k];
    }
    ((float4*)se0)[pos] = o0;
    ((float4*)se1)[pos] = o1;
}

// ---------------- bf16 MFMA GEMM (BM=128,BN=64,BK=32) + fused attention scores ----------------
// A fp32 or bf16, B/C bf16, fp32 accumulate. K%32==0, N%64==0, M guarded.
// SCORES: N-block == head; compute si/sj for this head from the C tile.
template <bool AF32, bool SCORES>
__global__ __launch_bounds__(256) void gemm_bf16(const void* __restrict__ Aptr,
                                                 const unsigned short* __restrict__ B,
                                                 unsigned short* __restrict__ C,
                                                 const float* __restrict__ avec,
                                                 float* __restrict__ si, float* __restrict__ sj,
                                                 int M, int N, int K) {
    __shared__ unsigned short As[128][40];
    __shared__ unsigned short Bs[64][40];   // [n][k] (transposed)
    __shared__ unsigned short Cs[128][72];
    __shared__ float sa[128];
    int tid = threadIdx.x;
    if (SCORES && tid < 128) sa[tid] = avec[blockIdx.y * 144 + tid];
    int bm = blockIdx.x * 128, bn = blockIdx.y * 64;
    int w = tid >> 6, l = tid & 63;
    int wr = w * 32;
    int lr = l & 15, lk = (l >> 4) * 8;
    f32x4 acc[2][4] = {};
    int ar = tid >> 1, akc = (tid & 1) * 16;      // A stage: row 0..127, k half
    int bk = tid >> 3, bn8 = tid & 7, bnc = bn8 * 8;

    for (int k0 = 0; k0 < K; k0 += 32) {
        bf16x8 av0 = {}, av1 = {};
        if (bm + ar < M) {
            if constexpr (AF32) {
                const float* Af = (const float*)Aptr + (size_t)(bm + ar) * K + k0 + akc;
                float4 f0 = ((const float4*)Af)[0];
                float4 f1 = ((const float4*)Af)[1];
                float4 f2 = ((const float4*)Af)[2];
                float4 f3 = ((const float4*)Af)[3];
                av0[0] = (short)f2bf(f0.x); av0[1] = (short)f2bf(f0.y);
                av0[2] = (short)f2bf(f0.z); av0[3] = (short)f2bf(f0.w);
                av0[4] = (short)f2bf(f1.x); av0[5] = (short)f2bf(f1.y);
                av0[6] = (short)f2bf(f1.z); av0[7] = (short)f2bf(f1.w);
                av1[0] = (short)f2bf(f2.x); av1[1] = (short)f2bf(f2.y);
                av1[2] = (short)f2bf(f2.z); av1[3] = (short)f2bf(f2.w);
                av1[4] = (short)f2bf(f3.x); av1[5] = (short)f2bf(f3.y);
                av1[6] = (short)f2bf(f3.z); av1[7] = (short)f2bf(f3.w);
            } else {
                const unsigned short* Ab = (const unsigned short*)Aptr + (size_t)(bm + ar) * K + k0 + akc;
                av0 = *(const bf16x8*)Ab;
                av1 = *(const bf16x8*)(Ab + 8);
            }
        }
        *(bf16x8*)&As[ar][akc] = av0;
        *(bf16x8*)&As[ar][akc + 8] = av1;
        bf16x8 bv = *(const bf16x8*)(B + (size_t)(k0 + bk) * N + bn + bnc);
#pragma unroll
        for (int j = 0; j < 8; ++j) {
            int jj = (j + bn8) & 7;  // rotate write order to spread banks
            Bs[bnc + jj][bk] = (unsigned short)bv[jj];
        }
        __syncthreads();
        bf16x8 a0 = *(const bf16x8*)&As[wr + lr][lk];
        bf16x8 a1 = *(const bf16x8*)&As[wr + 16 + lr][lk];
        bf16x8 b0 = *(const bf16x8*)&Bs[lr][lk];
        bf16x8 b1 = *(const bf16x8*)&Bs[16 + lr][lk];
        bf16x8 b2 = *(const bf16x8*)&Bs[32 + lr][lk];
        bf16x8 b3 = *(const bf16x8*)&Bs[48 + lr][lk];
        acc[0][0] = __builtin_amdgcn_mfma_f32_16x16x32_bf16(a0, b0, acc[0][0], 0, 0, 0);
        acc[0][1] = __builtin_amdgcn_mfma_f32_16x16x32_bf16(a0, b1, acc[0][1], 0, 0, 0);
        acc[0][2] = __builtin_amdgcn_mfma_f32_16x16x32_bf16(a0, b2, acc[0][2], 0, 0, 0);
        acc[0][3] = __builtin_amdgcn_mfma_f32_16x16x32_bf16(a0, b3, acc[0][3], 0, 0, 0);
        acc[1][0] = __builtin_amdgcn_mfma_f32_16x16x32_bf16(a1, b0, acc[1][0], 0, 0, 0);
        acc[1][1] = __builtin_amdgcn_mfma_f32_16x16x32_bf16(a1, b1, acc[1][1], 0, 0, 0);
        acc[1][2] = __builtin_amdgcn_mfma_f32_16x16x32_bf16(a1, b2, acc[1][2], 0, 0, 0);
        acc[1][3] = __builtin_amdgcn_mfma_f32_16x16x32_bf16(a1, b3, acc[1][3], 0, 0, 0);
        __syncthreads();
    }
    // D layout: col = lane&15, row = (lane>>4)*4 + reg
#pragma unroll
    for (int i = 0; i < 2; ++i)
#pragma unroll
        for (int j = 0; j < 4; ++j)
#pragma unroll
            for (int r = 0; r < 4; ++r)
                Cs[wr + i * 16 + (l >> 4) * 4 + r][j * 16 + (l & 15)] = f2bf(acc[i][j][r]);
    __syncthreads();
    {
        int row = tid >> 3, cc = (tid & 7) * 8;
#pragma unroll
        for (int p = 0; p < 4; ++p, row += 32) {
            if (bm + row < M) {
                bf16x8 o = *(const bf16x8*)&Cs[row][cc];
                *(bf16x8*)(C + (size_t)(bm + row) * N + bn + cc) = o;
            }
        }
    }
    if (SCORES) {
        int r = tid >> 1, half = tid & 1;
        float s0 = 0.f, s1 = 0.f;
#pragma unroll
        for (int k = 0; k < 32; ++k) {
            float f = bf2f(Cs[r][half * 32 + k]);
            s0 += f * sa[half * 32 + k];
            s1 += f * sa[64 + half * 32 + k];
        }
        s0 += __shfl_xor(s0, 1, 64);
        s1 += __shfl_xor(s1, 1, 64);
        if (half == 0 && bm + r < M) {
            si[(size_t)(bm + r) * 4 + blockIdx.y] = s0;
            sj[(size_t)(bm + r) * 4 + blockIdx.y] = s1;
        }
    }
}

// ---------------- edge aggregation + fused attention, 4 heads, concat + ELU ----------------
// one wave per node, 4 edge-slots x 16 lanes; attention computed inline per edge
// (s == v is wave-uniform; sj[u]/se[i] are 16B broadcast loads hidden under the row gather)
__global__ __launch_bounds__(256) void edge_agg_concat(
    const unsigned short* __restrict__ Whb, const float* __restrict__ sev,
    const float* __restrict__ si, const float* __restrict__ sj,
    const int* __restrict__ row_ptr, const int* __restrict__ dstp,
    unsigned short* __restrict__ out) {
    int v = blockIdx.x * 4 + (threadIdx.x >> 6);
    if (v >= N_NODES) return;
    int l = threadIdx.x & 63;
    int slot = l >> 4, p = l & 15;
    int beg = row_ptr[v], end = row_ptr[v + 1];
    float4 si4 = ((const float4*)si)[v];
    float acc0[8] = {}, acc1[8] = {};
    int i = beg + slot;
    int u_n = 0;
    float4 se_n = make_float4(0.f, 0.f, 0.f, 0.f), sj_n = se_n;
    if (i < end) {
        u_n = dstp[i];
        se_n = ((const float4*)sev)[i];
        sj_n = ((const float4*)sj)[u_n];
    }
    for (; i < end; i += 4) {
        int u = u_n;
        float4 se4 = se_n, sj4 = sj_n;
        if (i + 4 < end) {
            u_n = dstp[i + 4];
            se_n = ((const float4*)sev)[i + 4];
            sj_n = ((const float4*)sj)[u_n];
        }
        float t0 = si4.x + sj4.x + se4.x;
        float t1 = si4.y + sj4.y + se4.y;
        float t2 = si4.z + sj4.z + se4.z;
        float t3 = si4.w + sj4.w + se4.w;
        t0 = t0 > 0.f ? t0 : LRELU_ALPHA * t0;
        t1 = t1 > 0.f ? t1 : LRELU_ALPHA * t1;
        t2 = t2 > 0.f ? t2 : LRELU_ALPHA * t2;
        t3 = t3 > 0.f ? t3 : LRELU_ALPHA * t3;
        float m = fmaxf(fmaxf(t0, t1), fmaxf(t2, t3));
        float p0 = __expf(t0 - m), p1 = __expf(t1 - m), p2 = __expf(t2 - m), p3 = __expf(t3 - m);
        float inv = 1.0f / (p0 + p1 + p2 + p3);
        const unsigned short* row = Whb + (size_t)u * 256;
        u16x8 w0 = *(const u16x8*)(row + p * 8);         // heads 0/1
        u16x8 w1 = *(const u16x8*)(row + 128 + p * 8);   // heads 2/3
        float atA = ((p & 8) ? p1 : p0) * inv;
        float atB = ((p & 8) ? p3 : p2) * inv;
#pragma unroll
        for (int j = 0; j < 8; ++j) acc0[j] += atA * bf2f(w0[j]);
#pragma unroll
        for (int j = 0; j < 8; ++j) acc1[j] += atB * bf2f(w1[j]);
    }
#pragma unroll
    for (int j = 0; j < 8; ++j) {
        acc0[j] += __shfl_xor(acc0[j], 16, 64);
        acc0[j] += __shfl_xor(acc0[j], 32, 64);
        acc1[j] += __shfl_xor(acc1[j], 16, 64);
        acc1[j] += __shfl_xor(acc1[j], 32, 64);
    }
    if (slot == 0) {
        u16x8 o0, o1;
#pragma unroll
        for (int j = 0; j < 8; ++j) {
            o0[j] = f2bf(eluf(acc0[j]));
            o1[j] = f2bf(eluf(acc1[j]));
        }
        *(u16x8*)(out + (size_t)v * 256 + p * 8) = o0;
        *(u16x8*)(out + (size_t)v * 256 + 128 + p * 8) = o1;
    }
}

// ---------------- edge aggregation, single head: 8 edges in flight ----------------
__global__ __launch_bounds__(256) void edge_agg_single(
    const unsigned short* __restrict__ Whb, const int* __restrict__ row_ptr,
    const int* __restrict__ dstp, float* __restrict__ out) {
    int v = blockIdx.x * 4 + (threadIdx.x >> 6);
    if (v >= N_NODES) return;
    int l = threadIdx.x & 63;
    int slot = l >> 3, p = l & 7;
    int beg = row_ptr[v], end = row_ptr[v + 1];
    float acc[8] = {};
    int i = beg + slot;
    int u_n = 0;
    if (i < end) u_n = dstp[i];
    for (; i < end; i += 8) {
        int u = u_n;
        if (i + 8 < end) u_n = dstp[i + 8];
        u16x8 w = *(const u16x8*)(Whb + (size_t)u * 64 + p * 8);
#pragma unroll
        for (int j = 0; j < 8; ++j) acc[j] += bf2f(w[j]);
    }
#pragma unroll
    for (int j = 0; j < 8; ++j) {
        acc[j] += __shfl_xor(acc[j], 8, 64);
        acc[j] += __shfl_xor(acc[j], 16, 64);
        acc[j] += __shfl_xor(acc[j], 32, 64);
    }
    if (l < 8) {
        float4 o0 = make_float4(acc[0], acc[1], acc[2], acc[3]);
        float4 o1 = make_float4(acc[4], acc[5], acc[6], acc[7]);
        *(float4*)(out + (size_t)v * 64 + p * 8) = o0;
        *(float4*)(out + (size_t)v * 64 + p * 8 + 4) = o1;
    }
}

// ---------------- mean pool per graph (batch sorted), 16 waves per graph ----------------
__global__ __launch_bounds__(1024) void pool_kernel(const float* __restrict__ h3,
                                                    const int* __restrict__ batch,
                                                    float* __restrict__ pooled) {
    int g = blockIdx.x;
    int lane = threadIdx.x & 63;
    int wave = threadIdx.x >> 6;
    int lo = 0, hi = N_NODES;
    while (lo < hi) { int mid = (lo + hi) >> 1; if (batch[mid] < g) lo = mid + 1; else hi = mid; }
    int start = lo;
    lo = start; hi = N_NODES;
    while (lo < hi) { int mid = (lo + hi) >> 1; if (batch[mid] < g + 1) lo = mid + 1; else hi = mid; }
    int endi = lo;
    float s = 0.f;
    for (int v = start + wave; v < endi; v += 16) s += h3[(size_t)v * 64 + lane];
    __shared__ float red[16][64];
    red[wave][lane] = s;
    __syncthreads();
    if (wave == 0) {
        float t = red[0][lane];
#pragma unroll
        for (int w = 1; w < 16; ++w) t += red[w][lane];
        float c = (float)((endi - start) > 1 ? (endi - start) : 1);
        pooled[g * 64 + lane] = t / c;
    }
}

// ---------------- classifier + log_softmax ----------------
__global__ void classify_kernel(const float* __restrict__ pooled, const float* __restrict__ cw,
                                const float* __restrict__ cb, float* __restrict__ out) {
    int g = threadIdx.x;
    if (g >= NUM_GRAPHS) return;
    float lg[NUM_CLASSES];
#pragma unroll
    for (int c = 0; c < NUM_CLASSES; ++c) lg[c] = cb[c];
    for (int d = 0; d < OUT_F; ++d) {
        float p = pooled[g * 64 + d];
#pragma unroll
        for (int c = 0; c < NUM_CLASSES; ++c) lg[c] += p * cw[d * NUM_CLASSES + c];
    }
    float m = lg[0];
#pragma unroll
    for (int c = 1; c < NUM_CLASSES; ++c) m = fmaxf(m, lg[c]);
    float s = 0.f;
#pragma unroll
    for (int c = 0; c < NUM_CLASSES; ++c) s += expf(lg[c] - m);
    float lse = m + logf(s);
#pragma unroll
    for (int c = 0; c < NUM_CLASSES; ++c) out[g * NUM_CLASSES + c] = lg[c] - lse;
}

extern "C" void kernel_launch(void* const* d_in, const int* in_sizes, int n_in,
                              void* d_out, int out_size, void* d_ws, size_t ws_size,
                              hipStream_t stream) {
    const float* x   = (const float*)d_in[0];
    const int*   ei  = (const int*)d_in[1];
    const float* ea  = (const float*)d_in[2];
    const int* batch = (const int*)d_in[3];
    const float* W0  = (const float*)d_in[4];
    const float* a0  = (const float*)d_in[5];
    const float* W1  = (const float*)d_in[6];
    const float* a1  = (const float*)d_in[7];
    const float* W2  = (const float*)d_in[8];
    const float* cw  = (const float*)d_in[10];
    const float* cb  = (const float*)d_in[11];
    float* out = (float*)d_out;

    const int* srcg = ei;
    const int* dstg = ei + N_EDGES;

    char* ws = (char*)d_ws;
    size_t off = 0;
    auto alloc = [&](size_t bytes) -> char* {
        char* p = ws + off;
        off += (bytes + 255) & ~(size_t)255;
        return p;
    };
    unsigned short* W0b  = (unsigned short*)alloc(256 * 256 * 2);
    unsigned short* W1b  = (unsigned short*)alloc(256 * 256 * 2);
    unsigned short* W2b  = (unsigned short*)alloc(256 * 64 * 2);
    unsigned short* Whb  = (unsigned short*)alloc((size_t)N_NODES * 256 * 2);
    unsigned short* hAb  = (unsigned short*)alloc((size_t)N_NODES * 256 * 2);
    unsigned short* hBb  = (unsigned short*)alloc((size_t)N_NODES * 256 * 2);
    unsigned short* Wh2b = (unsigned short*)alloc((size_t)N_NODES * 64 * 2);
    float* si   = (float*)alloc((size_t)N_NODES * HEADS * 4);
    float* sj   = (float*)alloc((size_t)N_NODES * HEADS * 4);
    float* se0  = (float*)alloc((size_t)N_EDGES * HEADS * 4);
    float* se1  = (float*)alloc((size_t)N_EDGES * HEADS * 4);
    int* row_ptr = (int*)alloc((N_NODES + 1) * 4);
    int* cursor  = (int*)alloc(N_NODES * 4);
    int* cnt  = (int*)alloc(N_NODES * 4);
    int* dstp = (int*)alloc(N_EDGES * 4);
    float* h3 = (float*)alloc((size_t)N_NODES * 64 * 4);
    float* pooled = (float*)alloc(NUM_GRAPHS * 64 * 4);

    // prep: weight converts + zero cnt (one dispatch)
    prep_kernel<<<144 + (N_NODES / 4 + 255) / 256, 256, 0, stream>>>(W0, W1, W2, W0b, W1b, W2b, cnt);

    // CSR build; scatter also precomputes both layers' edge-feature scores
    count_kernel<<<(N_EDGES + 255) / 256, 256, 0, stream>>>(srcg, cnt);
    scan_kernel<<<1, 1024, 0, stream>>>(cnt, row_ptr, cursor);
    scatter_kernel<<<(N_EDGES + 255) / 256, 256, 0, stream>>>(srcg, dstg, ea, a0, a1, cursor,
                                                              dstp, se0, se1);

    dim3 ggrid((N_NODES + 127) / 128, 4);
    dim3 ggrid2((N_NODES + 127) / 128, 1);
    int agb = (N_NODES + 3) / 4;

    // layer 0 (A = x fp32, scores fused)
    gemm_bf16<true, true><<<ggrid, 256, 0, stream>>>(x, W0b, Whb, a0, si, sj, N_NODES, 256, 256);
    edge_agg_concat<<<agb, 256, 0, stream>>>(Whb, se0, si, sj, row_ptr, dstp, hAb);

    // layer 1
    gemm_bf16<false, true><<<ggrid, 256, 0, stream>>>(hAb, W1b, Whb, a1, si, sj, N_NODES, 256, 256);
    edge_agg_concat<<<agb, 256, 0, stream>>>(Whb, se1, si, sj, row_ptr, dstp, hBb);

    // layer 2 (single head, att == 1, mean over 1 head = identity)
    gemm_bf16<false, false><<<ggrid2, 256, 0, stream>>>(hBb, W2b, Wh2b, nullptr, nullptr, nullptr,
                                                        N_NODES, 64, 256);
    edge_agg_single<<<agb, 256, 0, stream>>>(Wh2b, row_ptr, dstp, h3);

    // pooling + classifier
    pool_kernel<<<NUM_GRAPHS, 1024, 0, stream>>>(h3, batch, pooled);
    classify_kernel<<<1, 64, 0, stream>>>(pooled, cw, cb, out);
}